// Round 2
// baseline (10246.387 us; speedup 1.0000x reference)
//
#include <hip/hip_runtime.h>
#include <stdint.h>

// ---------------- problem constants ----------------
#define BSZ 64
#define TSEQ 512
#define KTAG 12
#define START_TAG 10
#define STOP_TAG 11

#define TPH 64   // timesteps per phase
#define NPH 8    // phases (TPH*NPH == TSEQ)
#define NWG 256
#define BLK 256

// ---------------- workspace layout (bytes) ----------------
// flags: 4 groups x 64 producers, each flag padded to 64 B -> 16 KB
#define FLAGS_BYTES 16384
#define FEATS_OFF FLAGS_BYTES                       // float feats [b][t][k]
#define FEATS_BYTES (BSZ * TSEQ * KTAG * 4)         // 1572864
#define HBUF_OFF (FEATS_OFF + FEATS_BYTES)          // 1589248
#define HBUF_BYTES (2 * 512 * 128 * 4)              // 524288 (ping-pong h [u][ch])
#define CBUF_OFF (HBUF_OFF + HBUF_BYTES)            // 2113536
#define CBUF_BYTES (NWG * 256 * 4)                  // 262144
#define BPS_OFF (CBUF_OFF + CBUF_BYTES)             // 2375680
#define BPS_BYTES (TSEQ * BSZ * KTAG)               // 393216
#define XP_OFF (BPS_OFF + BPS_BYTES)                // 2768896
#define XP_BYTES (64 * 4 * TPH * 32 * 32 * 4)       // 67108864
#define HSAVE_OFF (XP_OFF + XP_BYTES)               // 69877760
#define HSAVE_BYTES (TSEQ * 128 * 512 * 4)          // 134217728; total ~194.6 MB

// ---------------- LSTM phase kernel LDS (float offsets) ----------------
#define LW_OFF 0        // 16384: Wh slice [e 512][32 j] quad-XOR swizzled
#define LH_OFF 16384    // 16384: h slice  [e 512][32 c] quad-XOR swizzled
#define LG_OFF 32768    // 4096 : per-wave partial gates [4][32 j][32 c]
#define LXP_OFF 36864   // 1056 : xp tile [32 c][33]
#define LCS_OFF 37920   // 256  : c-state [8 uu][32 c]
#define LBI_OFF 38176   // 32   : bias
#define LSL_OFF 38208   // 32 ints: seq lens
#define LMX_OFF 38240   // 1 int : group max seq len
#define LSTM_SMEM_FLOATS 38244
#define LSTM_SMEM_BYTES (LSTM_SMEM_FLOATS * 4)      // 152976 < 160 KiB

// ---------------- pre-GEMM kernel LDS ----------------
#define PW_OFF 0        // 16384: Wi slice [e 512][32 j] swizzled
#define PE_OFF 16384    // 8192 : emb chunk [e 128][64 r] swizzled
#define PT_OFF 24576    // 64 ints: tokens
#define PRE_SMEM_FLOATS 24640
#define PRE_SMEM_BYTES (PRE_SMEM_FLOATS * 4)        // 98560

__device__ __forceinline__ float sigm(float x) { return 1.f / (1.f + expf(-x)); }

// ---------------- init: h0 -> hbuf[0], c0 -> cbuf ----------------
__global__ void init_state(const float* __restrict__ h0, const float* __restrict__ c0,
                           float* __restrict__ hbuf, float* __restrict__ cbuf) {
  int i = blockIdx.x * 256 + threadIdx.x;
  if (i < 65536) {
    int u = i >> 7, ch = i & 127;
    int ct = ch >> 5, c = ch & 31;
    int dir = ct >> 1, b = ((ct & 1) << 5) + c;
    hbuf[i] = h0[(dir * 64 + b) * 512 + u];
  } else {
    int j = i - 65536;
    int wg = j >> 8, r = j & 255;
    int ct = wg >> 6, ut = wg & 63;
    int uu = r >> 5, c = r & 31;
    int dir = ct >> 1, b = ((ct & 1) << 5) + c;
    cbuf[j] = c0[(dir * 64 + b) * 512 + ut * 8 + uu];
  }
}

// ---------------- pre-GEMM: xp[ut][ct][taul][c][j] = emb(b, pos(tau)) @ Wi_slice ----------------
__global__ __launch_bounds__(256, 1) void pre_gemm(
    int phase, const int* __restrict__ sentence, const int* __restrict__ seq_lens,
    const float* __restrict__ embed, const float* __restrict__ Wi_f,
    const float* __restrict__ Wi_b, float* __restrict__ xp) {
  extern __shared__ float sm[];
  float* wiS = sm + PW_OFF;
  float* embS = sm + PE_OFF;
  int* tokS = (int*)(sm + PT_OFF);

  const int tid = threadIdx.x;
  const int dirut = blockIdx.x;            // 128
  const int dir = dirut >> 6, ut = dirut & 63;
  const int b = blockIdx.y;                // 64
  const int sl = seq_lens[b];
  const int t0 = phase * TPH;
  if (t0 >= sl) return;
  const int u0 = ut * 8;
  const int ct = dir * 2 + (b >> 5);
  const int cc = b & 31;
  const float* Wi = dir ? Wi_b : Wi_f;

  for (int j = 0; j < 32; ++j) {
    int row = (j >> 3) * 512 + u0 + (j & 7);
    for (int ee = tid; ee < 512; ee += BLK)
      wiS[ee * 32 + ((((j >> 2) ^ (ee & 7)) << 2) | (j & 3))] = Wi[row * 512 + ee];
  }
  if (tid < 64) {
    int tg = t0 + tid;
    int pos = dir ? (sl - 1 - tg) : tg;
    pos = min(max(pos, 0), 511);
    tokS[tid] = sentence[b * 512 + pos];
  }
  __syncthreads();

  const int lane = tid & 63, w = tid >> 6;
  const int es = lane >> 3, tl8 = lane & 7;
  const int tile = w * 8 + tl8;
  const int jt = tile & 3, rt = tile >> 2;
  const int rr = tid & 63, seg = tid >> 6;

  float acc[8][8];
#pragma unroll
  for (int a = 0; a < 8; ++a)
#pragma unroll
    for (int b2 = 0; b2 < 8; ++b2) acc[a][b2] = 0.f;

  const int mytok = tokS[rr];
  float4 vb[2][8];
  {
    const float* src = embed + (size_t)mytok * 512 + seg * 32;
#pragma unroll
    for (int q = 0; q < 8; ++q) vb[0][q] = *(const float4*)(src + q * 4);
  }
  const int rq = rr >> 2, rl = rr & 3;
  const float* wp0b = wiS + (((jt * 2) ^ es) << 2) + es * 32;
  const float* wp1b = wiS + (((jt * 2 + 1) ^ es) << 2) + es * 32;
  const float* ep0 = embS + es * 64 + ((((rt * 2) ^ es)) << 2);
  const float* ep1 = embS + es * 64 + ((((rt * 2 + 1) ^ es)) << 2);

#pragma unroll
  for (int kk = 0; kk < 4; ++kk) {
    if (kk) __syncthreads();
#pragma unroll
    for (int q = 0; q < 8; ++q) {
      const int el = seg * 32 + q * 4;
      const float4 v = vb[kk & 1][q];
      embS[(el + 0) * 64 + (((rq ^ ((el + 0) & 7)) << 2) | rl)] = v.x;
      embS[(el + 1) * 64 + (((rq ^ ((el + 1) & 7)) << 2) | rl)] = v.y;
      embS[(el + 2) * 64 + (((rq ^ ((el + 2) & 7)) << 2) | rl)] = v.z;
      embS[(el + 3) * 64 + (((rq ^ ((el + 3) & 7)) << 2) | rl)] = v.w;
    }
    if (kk < 3) {
      const float* src = embed + (size_t)mytok * 512 + (kk + 1) * 128 + seg * 32;
#pragma unroll
      for (int q = 0; q < 8; ++q) vb[(kk + 1) & 1][q] = *(const float4*)(src + q * 4);
    }
    __syncthreads();
    const float* wp0 = wp0b + kk * 128 * 32;
    const float* wp1 = wp1b + kk * 128 * 32;
#pragma unroll
    for (int i = 0; i < 16; ++i) {
      const float4 w0 = *(const float4*)(wp0 + i * 256);
      const float4 w1 = *(const float4*)(wp1 + i * 256);
      const float4 x0 = *(const float4*)(ep0 + i * 512);
      const float4 x1 = *(const float4*)(ep1 + i * 512);
      float wv[8] = {w0.x, w0.y, w0.z, w0.w, w1.x, w1.y, w1.z, w1.w};
      float xv[8] = {x0.x, x0.y, x0.z, x0.w, x1.x, x1.y, x1.z, x1.w};
#pragma unroll
      for (int a = 0; a < 8; ++a)
#pragma unroll
        for (int b2 = 0; b2 < 8; ++b2) acc[a][b2] = fmaf(wv[a], xv[b2], acc[a][b2]);
    }
  }

  const bool hi1 = (lane & 8) != 0;
  float r1[4][8];
#pragma unroll
  for (int a = 0; a < 4; ++a)
#pragma unroll
    for (int b2 = 0; b2 < 8; ++b2) {
      float sendv = hi1 ? acc[a][b2] : acc[a + 4][b2];
      float keepv = hi1 ? acc[a + 4][b2] : acc[a][b2];
      r1[a][b2] = keepv + __shfl_xor(sendv, 8, 64);
    }
  const bool hi2 = (lane & 16) != 0;
  float r2[4][4];
#pragma unroll
  for (int a = 0; a < 4; ++a)
#pragma unroll
    for (int b2 = 0; b2 < 4; ++b2) {
      float sendv = hi2 ? r1[a][b2] : r1[a][b2 + 4];
      float keepv = hi2 ? r1[a][b2 + 4] : r1[a][b2];
      r2[a][b2] = keepv + __shfl_xor(sendv, 16, 64);
    }
  const bool hi3 = (lane & 32) != 0;
  float r3[2][4];
#pragma unroll
  for (int a = 0; a < 2; ++a)
#pragma unroll
    for (int b2 = 0; b2 < 4; ++b2) {
      float sendv = hi3 ? r2[a][b2] : r2[a + 2][b2];
      float keepv = hi3 ? r2[a + 2][b2] : r2[a][b2];
      r3[a][b2] = keepv + __shfl_xor(sendv, 32, 64);
    }
  const int ab1 = hi1 ? 4 : 0, bb = hi2 ? 4 : 0, ab2 = hi3 ? 2 : 0;
  const size_t base = (size_t)(ut * 4 + ct) * (TPH * 1024) + (size_t)cc * 32;
#pragma unroll
  for (int a = 0; a < 2; ++a)
#pragma unroll
    for (int b2 = 0; b2 < 4; ++b2) {
      int tau = rt * 8 + bb + b2;
      if (t0 + tau < sl)
        xp[base + (size_t)tau * 1024 + (jt * 8 + ab1 + ab2 + a)] = r3[a][b2];
    }
}

// ---------------- LSTM recurrent phase (cooperative, 256 WGs) ----------------
// Sync: per-group flag array, 64 producers x 64B-padded u32 epoch flags.
__global__ __launch_bounds__(BLK, 1) void lstm_phase(
    int phase, const int* __restrict__ seq_lens, const float* __restrict__ Wh_f,
    const float* __restrict__ Wh_b, const float* __restrict__ b_f,
    const float* __restrict__ b_b, const float* __restrict__ xp,
    float* __restrict__ hbuf, float* __restrict__ cbuf, float* __restrict__ hsave,
    unsigned* __restrict__ bar) {
  extern __shared__ float sm[];
  float* wS = sm + LW_OFF;
  float* hS = sm + LH_OFF;
  float* gS = sm + LG_OFF;
  float* xpS = sm + LXP_OFF;
  float* cstS = sm + LCS_OFF;
  float* biasS = sm + LBI_OFF;
  int* slS = (int*)(sm + LSL_OFF);
  int* mslS = (int*)(sm + LMX_OFF);

  const int tid = threadIdx.x;
  const int bid = blockIdx.x;
  const int ut = bid & 63, ct = bid >> 6;
  const int u0 = ut * 8, ch0 = ct * 32, dir = ct >> 1;
  const float* Wh = dir ? Wh_b : Wh_f;
  const float* bb = dir ? b_b : b_f;

  if (tid < 32) slS[tid] = seq_lens[((ct & 1) << 5) + tid];
  __syncthreads();
  if (tid == 0) {
    int m = 0;
    for (int c = 0; c < 32; ++c) m = max(m, slS[c]);
    *mslS = m;
  }
  __syncthreads();
  const int gmax = *mslS;
  const int t0 = phase * TPH;
  if (t0 >= gmax) return;

  for (int j = 0; j < 32; ++j) {
    int row = (j >> 3) * 512 + u0 + (j & 7);
    for (int ee = tid; ee < 512; ee += BLK)
      wS[ee * 32 + ((((j >> 2) ^ (ee & 7)) << 2) | (j & 3))] = Wh[row * 512 + ee];
  }
  if (tid < 32) biasS[tid] = bb[(tid >> 3) * 512 + u0 + (tid & 7)];
  cstS[tid] = cbuf[bid * 256 + tid];
  __syncthreads();

  const int lane = tid & 63, w = tid >> 6;
  const int tp = lane & 15, jt = tp & 3, ct2 = tp >> 2;
  const int es = w * 4 + (lane >> 4);
  const int esw = es & 7;
  const int nst = min(TPH, gmax - t0);

  const float* wpA = wS + es * 32 + (((jt * 2) ^ esw) << 2);
  const float* wpB = wS + es * 32 + (((jt * 2 + 1) ^ esw) << 2);
  const float* hpA = hS + es * 32 + (((ct2 * 2) ^ esw) << 2);
  const float* hpB = hS + es * 32 + (((ct2 * 2 + 1) ^ esw) << 2);

  float4 xr = *(const float4*)(xp + ((size_t)(ut * 4 + ct) * TPH + 0) * 1024 + tid * 4);

  for (int tl = 0; tl < nst; ++tl) {
    const int t = t0 + tl;
    const float* hcur = hbuf + (t & 1) * 65536;
    float* hnxt = hbuf + ((t + 1) & 1) * 65536;

    // ---- wait for all 64 producers of h(t): flag[ut'] >= t (one lane each) ----
    if (tid < 64) {
      const unsigned* fp = &bar[ct * 1024 + tid * 16];
      while (__hip_atomic_load(fp, __ATOMIC_RELAXED, __HIP_MEMORY_SCOPE_AGENT) <
             (unsigned)t) {}
    }
    if (tid == 0) __builtin_amdgcn_fence(__ATOMIC_ACQUIRE, "agent");
    __syncthreads();

    // [A] bulk-stage h slice -> LDS (swizzled); store xp regs; prefetch next xp
#pragma unroll
    for (int it = 0; it < 16; ++it) {
      int u = it * 32 + (tid >> 3), q = tid & 7;
      float4 hv = *(const float4*)(hcur + u * 128 + ch0 + q * 4);
      *(float4*)(hS + u * 32 + ((q ^ (u & 7)) << 2)) = hv;
    }
    {
      int c = tid >> 3, j4 = tid & 7;
      float* d = xpS + c * 33 + j4 * 4;
      d[0] = xr.x; d[1] = xr.y; d[2] = xr.z; d[3] = xr.w;
    }
    if (tl + 1 < nst)
      xr = *(const float4*)(xp + ((size_t)(ut * 4 + ct) * TPH + (tl + 1)) * 1024 + tid * 4);
    __syncthreads();

    // [B] 32x32x512 matmul: 8x8 register tile
    float acc[8][8];
#pragma unroll
    for (int a = 0; a < 8; ++a)
#pragma unroll
      for (int b2 = 0; b2 < 8; ++b2) acc[a][b2] = 0.f;
    for (int io = 0; io < 4; ++io) {
#pragma unroll
      for (int ii = 0; ii < 8; ++ii) {
        const int off = (io * 8 + ii) * 512;
        const float4 w0 = *(const float4*)(wpA + off);
        const float4 w1 = *(const float4*)(wpB + off);
        const float4 x0 = *(const float4*)(hpA + off);
        const float4 x1 = *(const float4*)(hpB + off);
        float wv[8] = {w0.x, w0.y, w0.z, w0.w, w1.x, w1.y, w1.z, w1.w};
        float xv[8] = {x0.x, x0.y, x0.z, x0.w, x1.x, x1.y, x1.z, x1.w};
#pragma unroll
        for (int a = 0; a < 8; ++a)
#pragma unroll
          for (int b2 = 0; b2 < 8; ++b2) acc[a][b2] = fmaf(wv[a], xv[b2], acc[a][b2]);
      }
    }

    // in-wave butterfly reduce-scatter over es lane-bits 16,32
    const bool hi1 = (lane & 16) != 0;
    float r1[4][8];
#pragma unroll
    for (int a = 0; a < 4; ++a)
#pragma unroll
      for (int b2 = 0; b2 < 8; ++b2) {
        float sendv = hi1 ? acc[a][b2] : acc[a + 4][b2];
        float keepv = hi1 ? acc[a + 4][b2] : acc[a][b2];
        r1[a][b2] = keepv + __shfl_xor(sendv, 16, 64);
      }
    const bool hi2 = (lane & 32) != 0;
    float r2[4][4];
#pragma unroll
    for (int a = 0; a < 4; ++a)
#pragma unroll
      for (int b2 = 0; b2 < 4; ++b2) {
        float sendv = hi2 ? r1[a][b2] : r1[a][b2 + 4];
        float keepv = hi2 ? r1[a][b2 + 4] : r1[a][b2];
        r2[a][b2] = keepv + __shfl_xor(sendv, 32, 64);
      }
    const int ab = hi1 ? 4 : 0, bbs = hi2 ? 4 : 0;
#pragma unroll
    for (int a = 0; a < 4; ++a) {
      float4 v = make_float4(r2[a][0], r2[a][1], r2[a][2], r2[a][3]);
      *(float4*)(gS + w * 1024 + (jt * 8 + ab + a) * 32 + ct2 * 8 + bbs) = v;
    }
    __syncthreads();

    // [C] epilogue: combine 4 wave-partials + xp + bias -> gates -> c,h
    {
      const int uu = tid >> 5, c = tid & 31;
      const int slc = slS[c];
      float s0 = 0.f, s1 = 0.f, s2 = 0.f, s3 = 0.f;
#pragma unroll
      for (int w2 = 0; w2 < 4; ++w2) {
        const float* gp = gS + w2 * 1024 + uu * 32 + c;
        s0 += gp[0];
        s1 += gp[256];
        s2 += gp[512];
        s3 += gp[768];
      }
      const bool xvalid = (t < slc);
      float x0 = xvalid ? xpS[c * 33 + uu] : 0.f;
      float x1 = xvalid ? xpS[c * 33 + 8 + uu] : 0.f;
      float x2 = xvalid ? xpS[c * 33 + 16 + uu] : 0.f;
      float x3 = xvalid ? xpS[c * 33 + 24 + uu] : 0.f;
      float iv = s0 + x0 + biasS[uu];
      float fv = s1 + x1 + biasS[8 + uu];
      float gv = s2 + x2 + biasS[16 + uu];
      float ov = s3 + x3 + biasS[24 + uu];
      float cn = sigm(fv) * cstS[uu * 32 + c] + sigm(iv) * tanhf(gv);
      float hn = sigm(ov) * tanhf(cn);
      cstS[uu * 32 + c] = cn;
      hnxt[(u0 + uu) * 128 + ch0 + c] = hn;
      hsave[(size_t)t * 65536 + (size_t)(ch0 + c) * 512 + u0 + uu] = hn;
    }
    __syncthreads();  // drains all waves' stores (vmcnt0 before barrier)

    if (tid == 0) {
      __builtin_amdgcn_fence(__ATOMIC_RELEASE, "agent");
      __hip_atomic_store(&bar[ct * 1024 + ut * 16], (unsigned)(t + 1),
                         __ATOMIC_RELAXED, __HIP_MEMORY_SCOPE_AGENT);
    }
  }
  cbuf[bid * 256 + tid] = cstS[tid];
}

// ---------------- feats = H @ W_out.T + b_out (deterministic fp32) ----------------
__global__ __launch_bounds__(256) void feats_kernel(
    const int* __restrict__ seq_lens, const float* __restrict__ W_out,
    const float* __restrict__ b_out, const float* __restrict__ hsave,
    float* __restrict__ featsF) {
  __shared__ float wL[1024 * 12];  // [hd][k], 48 KB
  __shared__ float bL[12];
  const int tid = threadIdx.x;
  const int b = blockIdx.x, py = blockIdx.y;
  const int sl = seq_lens[b];
  const int p0 = py * 64;
  if (p0 >= sl) return;
  for (int i = tid; i < 12288; i += 256) wL[(i & 1023) * 12 + (i >> 10)] = W_out[i];
  if (tid < 12) bL[tid] = b_out[tid];
  __syncthreads();
  const int ch0 = (b >> 5) * 32 + (b & 31);
  const int ch1 = (2 + (b >> 5)) * 32 + (b & 31);
  if (tid < 192) {
    const int pl = tid / 12, k = tid % 12;
    for (int pass = 0; pass < 4; ++pass) {
      const int p = p0 + pass * 16 + pl;
      if (p < sl) {
        const float* h0p = hsave + (size_t)p * 65536 + (size_t)ch0 * 512;
        const float* h1p = hsave + (size_t)(sl - 1 - p) * 65536 + (size_t)ch1 * 512;
        float acc = bL[k];
        for (int u = 0; u < 512; u += 4) {
          float4 a = *(const float4*)(h0p + u);
          acc = fmaf(a.x, wL[(u + 0) * 12 + k], acc);
          acc = fmaf(a.y, wL[(u + 1) * 12 + k], acc);
          acc = fmaf(a.z, wL[(u + 2) * 12 + k], acc);
          acc = fmaf(a.w, wL[(u + 3) * 12 + k], acc);
          float4 bv = *(const float4*)(h1p + u);
          acc = fmaf(bv.x, wL[(512 + u + 0) * 12 + k], acc);
          acc = fmaf(bv.y, wL[(512 + u + 1) * 12 + k], acc);
          acc = fmaf(bv.z, wL[(512 + u + 2) * 12 + k], acc);
          acc = fmaf(bv.w, wL[(512 + u + 3) * 12 + k], acc);
        }
        featsF[((size_t)b * 512 + p) * 12 + k] = acc;
      }
    }
  }
}

// ---------------- viterbi ----------------
__global__ __launch_bounds__(768) void viterbi_kernel(
    const int* __restrict__ seq_lens, const float* __restrict__ transitions,
    const float* __restrict__ featsF, unsigned char* __restrict__ bps,
    float* __restrict__ out) {
  __shared__ float fvL[64 * 13];
  __shared__ float tmL[64 * 13];
  __shared__ float trL[144];
  __shared__ int slL[64];
  __shared__ unsigned char tagL[64 * 512];
  const int tid = threadIdx.x;
  const int b = tid & 63, k = tid >> 6;
  if (tid < 144) trL[tid] = transitions[tid];
  if (tid < 64) slL[tid] = seq_lens[tid];
  fvL[b * 13 + k] = (k == START_TAG) ? 0.f : -10000.f;
  __syncthreads();
  for (int t = 0; t < TSEQ; ++t) {
    bool m = t < slL[b];
    float best = fvL[b * 13 + 0] + trL[k * 12 + 0];
    int arg = 0;
#pragma unroll
    for (int p = 1; p < 12; ++p) {
      float v = fvL[b * 13 + p] + trL[k * 12 + p];
      if (v > best) { best = v; arg = p; }
    }
    float feat = featsF[((size_t)b * 512 + t) * 12 + k];
    float nv = m ? (best + feat) : fvL[b * 13 + k];
    bps[((size_t)t * 64 + b) * 12 + k] = (unsigned char)(m ? arg : k);
    __syncthreads();
    fvL[b * 13 + k] = nv;
    __syncthreads();
  }
  tmL[b * 13 + k] = fvL[b * 13 + k] + trL[STOP_TAG * 12 + k];
  __syncthreads();
  if (tid < 64) {
    float best = tmL[tid * 13 + 0];
    int arg = 0;
    for (int kk = 1; kk < 12; ++kk) {
      float v = tmL[tid * 13 + kk];
      if (v > best) { best = v; arg = kk; }
    }
    out[tid] = best;
    int tag = arg;
    const uint32_t* rowp = (const uint32_t*)bps;
    uint32_t r0, r1, r2;
    { int off = (511 * 64 + tid) * 3; r0 = rowp[off]; r1 = rowp[off + 1]; r2 = rowp[off + 2]; }
    for (int t = 511; t >= 0; --t) {
      uint32_t n0 = 0, n1 = 0, n2 = 0;
      if (t > 0) {
        int off = ((t - 1) * 64 + tid) * 3;
        n0 = rowp[off]; n1 = rowp[off + 1]; n2 = rowp[off + 2];
      }
      tagL[tid * 512 + t] = (unsigned char)tag;
      uint32_t sel = (tag < 4) ? (r0 >> (tag * 8))
                   : (tag < 8) ? (r1 >> ((tag - 4) * 8))
                               : (r2 >> ((tag - 8) * 8));
      tag = (int)(sel & 0xffu);
      r0 = n0; r1 = n1; r2 = n2;
    }
  }
  __syncthreads();
  for (int idx = tid; idx < 64 * 512; idx += 768)
    out[64 + idx] = (float)tagL[idx];
}

extern "C" void kernel_launch(void* const* d_in, const int* in_sizes, int n_in,
                              void* d_out, int out_size, void* d_ws, size_t ws_size,
                              hipStream_t stream) {
  (void)in_sizes; (void)n_in; (void)out_size; (void)ws_size;
  const int* sentence = (const int*)d_in[0];
  const int* seq_lens = (const int*)d_in[1];
  const float* embed = (const float*)d_in[2];
  const float* Wi_f = (const float*)d_in[3];
  const float* Wh_f = (const float*)d_in[4];
  const float* b_f = (const float*)d_in[5];
  const float* Wi_b = (const float*)d_in[6];
  const float* Wh_b = (const float*)d_in[7];
  const float* b_b = (const float*)d_in[8];
  const float* h0 = (const float*)d_in[9];
  const float* c0 = (const float*)d_in[10];
  const float* W_out = (const float*)d_in[11];
  const float* b_out = (const float*)d_in[12];
  const float* trans = (const float*)d_in[13];

  char* ws = (char*)d_ws;
  unsigned* bar = (unsigned*)ws;
  float* featsF = (float*)(ws + FEATS_OFF);
  float* hbuf = (float*)(ws + HBUF_OFF);
  float* cbuf = (float*)(ws + CBUF_OFF);
  unsigned char* bps = (unsigned char*)(ws + BPS_OFF);
  float* xpw = (float*)(ws + XP_OFF);
  float* hsave = (float*)(ws + HSAVE_OFF);

  hipMemsetAsync(d_ws, 0, FLAGS_BYTES, stream);  // flags only

  hipFuncSetAttribute((const void*)lstm_phase,
                      hipFuncAttributeMaxDynamicSharedMemorySize, LSTM_SMEM_BYTES);
  hipFuncSetAttribute((const void*)pre_gemm,
                      hipFuncAttributeMaxDynamicSharedMemorySize, PRE_SMEM_BYTES);

  init_state<<<dim3(512), dim3(256), 0, stream>>>(h0, c0, hbuf, cbuf);

  for (int p = 0; p < NPH; ++p) {
    pre_gemm<<<dim3(128, 64), dim3(BLK), PRE_SMEM_BYTES, stream>>>(
        p, sentence, seq_lens, embed, Wi_f, Wi_b, xpw);
    int pv = p;
    void* kargs[] = {(void*)&pv,    (void*)&seq_lens, (void*)&Wh_f, (void*)&Wh_b,
                     (void*)&b_f,   (void*)&b_b,      (void*)&xpw,  (void*)&hbuf,
                     (void*)&cbuf,  (void*)&hsave,    (void*)&bar};
    hipLaunchCooperativeKernel((const void*)lstm_phase, dim3(NWG), dim3(BLK), kargs,
                               LSTM_SMEM_BYTES, stream);
  }
  feats_kernel<<<dim3(64, 8), dim3(256), 0, stream>>>(seq_lens, W_out, b_out, hsave,
                                                      featsF);
  viterbi_kernel<<<dim3(1), dim3(768), 0, stream>>>(seq_lens, trans, featsF, bps,
                                                    (float*)d_out);
}

// Round 3
// 9988.615 us; speedup vs baseline: 1.0258x; 1.0258x over previous
//
#include <hip/hip_runtime.h>
#include <stdint.h>

// ---------------- problem constants ----------------
#define BSZ 64
#define TSEQ 512
#define KTAG 12
#define START_TAG 10
#define STOP_TAG 11

#define TPH 64   // timesteps per phase
#define NPH 8    // phases (TPH*NPH == TSEQ)
#define NWG 256
#define BLK 256

// ---------------- workspace layout (bytes) ----------------
// bar: per ct (4): flag at [ct*256], root cnt [ct*256+16], sub cnt j at [ct*256+32+j*16]
#define BAR_BYTES 4096
#define FEATS_OFF BAR_BYTES
#define FEATS_BYTES (BSZ * TSEQ * KTAG * 4)         // 1572864 (float, zero-init)
#define CBUF_OFF (FEATS_OFF + FEATS_BYTES)          // 1576960
#define CBUF_BYTES (NWG * 256 * 4)                  // 262144
#define BPS_OFF (CBUF_OFF + CBUF_BYTES)             // 1839104
#define BPS_BYTES (TSEQ * BSZ * KTAG)               // 393216
#define XP_OFF (BPS_OFF + BPS_BYTES)                // 2232320
#define XP_BYTES (64 * 4 * TPH * 32 * 32 * 4)       // 67108864
#define HFULL_OFF (XP_OFF + XP_BYTES)               // 69341184
#define HFULL_BYTES ((TSEQ + 1) * 512 * 128 * 4)    // 134479872; total ~204 MB

// ---------------- LSTM phase kernel LDS (float offsets) ----------------
#define LW_OFF 0        // 16384: Wh slice [e 512][32 j] quad-XOR swizzled
#define LH_OFF 16384    // 16384: h slice  [e 512][32 c] quad-XOR swizzled
#define LG_OFF 32768    // 4096 : per-wave partial gates [4][32 j][32 c]
#define LXP_OFF 36864   // 1056 : xp tile [32 c][33]
#define LCS_OFF 37920   // 256  : c-state [8 uu][32 c]
#define LBI_OFF 38176   // 32   : bias
#define LSL_OFF 38208   // 32 ints: seq lens
#define LMX_OFF 38240   // 1 int : group max seq len
#define LSTM_SMEM_FLOATS 38244
#define LSTM_SMEM_BYTES (LSTM_SMEM_FLOATS * 4)      // 152976 < 160 KiB

// ---------------- pre-GEMM kernel LDS ----------------
#define PW_OFF 0        // 16384: Wi slice [e 512][32 j] swizzled
#define PE_OFF 16384    // 8192 : emb chunk [e 128][64 r] swizzled
#define PT_OFF 24576    // 64 ints: tokens
#define PRE_SMEM_FLOATS 24640
#define PRE_SMEM_BYTES (PRE_SMEM_FLOATS * 4)        // 98560

// ---------------- feats kernel LDS ----------------
#define FK_W_OFF 0      // 12*520 = 6240
#define FK_H_OFF 6240   // 512*33 = 16896
#define FK_SL_OFF 23136 // 32 ints
#define FK_FLOATS 23168
#define FK_SMEM_BYTES (FK_FLOATS * 4)               // 92672

__device__ __forceinline__ float sigm(float x) { return 1.f / (1.f + expf(-x)); }

// per-ct barrier over 64 WGs: two-level counters (8 subgroups x 8), single broadcast flag
__device__ __forceinline__ void gbar_ct(unsigned* bar, int ct, int sub, unsigned epoch) {
  __syncthreads();
  if (threadIdx.x == 0) {
    bool setter = false;
    __builtin_amdgcn_fence(__ATOMIC_RELEASE, "agent");
    unsigned o = __hip_atomic_fetch_add(&bar[ct * 256 + 32 + sub * 16], 1u,
                                        __ATOMIC_RELAXED, __HIP_MEMORY_SCOPE_AGENT);
    if (o == epoch * 8u - 1u) {
      unsigned r = __hip_atomic_fetch_add(&bar[ct * 256 + 16], 1u, __ATOMIC_RELAXED,
                                          __HIP_MEMORY_SCOPE_AGENT);
      if (r == epoch * 8u - 1u) {
        __builtin_amdgcn_fence(__ATOMIC_ACQUIRE, "agent");
        __hip_atomic_store(&bar[ct * 256], epoch, __ATOMIC_RELAXED,
                           __HIP_MEMORY_SCOPE_AGENT);
        setter = true;
      }
    }
    if (!setter) {
      while (__hip_atomic_load(&bar[ct * 256], __ATOMIC_RELAXED,
                               __HIP_MEMORY_SCOPE_AGENT) < epoch) {}
      __builtin_amdgcn_fence(__ATOMIC_ACQUIRE, "agent");
    }
  }
  __syncthreads();
}

// ---------------- init: h0 -> hfull slot 0, c0 -> cbuf ----------------
__global__ void init_state(const float* __restrict__ h0, const float* __restrict__ c0,
                           float* __restrict__ hfull, float* __restrict__ cbuf) {
  int i = blockIdx.x * 256 + threadIdx.x;
  if (i < 65536) {
    int u = i >> 7, ch = i & 127;
    int ct = ch >> 5, c = ch & 31;
    int dir = ct >> 1, b = ((ct & 1) << 5) + c;
    hfull[i] = h0[(dir * 64 + b) * 512 + u];
  } else {
    int j = i - 65536;
    int wg = j >> 8, r = j & 255;
    int ct = wg >> 6, ut = wg & 63;
    int uu = r >> 5, c = r & 31;
    int dir = ct >> 1, b = ((ct & 1) << 5) + c;
    cbuf[j] = c0[(dir * 64 + b) * 512 + ut * 8 + uu];
  }
}

// ---------------- pre-GEMM: xp[ut][ct][taul][c][j] = emb(b, pos(tau)) @ Wi_slice ----------------
__global__ __launch_bounds__(256, 1) void pre_gemm(
    int phase, const int* __restrict__ sentence, const int* __restrict__ seq_lens,
    const float* __restrict__ embed, const float* __restrict__ Wi_f,
    const float* __restrict__ Wi_b, float* __restrict__ xp) {
  extern __shared__ float sm[];
  float* wiS = sm + PW_OFF;
  float* embS = sm + PE_OFF;
  int* tokS = (int*)(sm + PT_OFF);

  const int tid = threadIdx.x;
  const int dirut = blockIdx.x;            // 128
  const int dir = dirut >> 6, ut = dirut & 63;
  const int b = blockIdx.y;                // 64
  const int sl = seq_lens[b];
  const int t0 = phase * TPH;
  if (t0 >= sl) return;
  const int u0 = ut * 8;
  const int ct = dir * 2 + (b >> 5);
  const int cc = b & 31;
  const float* Wi = dir ? Wi_b : Wi_f;

  for (int j = 0; j < 32; ++j) {
    int row = (j >> 3) * 512 + u0 + (j & 7);
    for (int ee = tid; ee < 512; ee += BLK)
      wiS[ee * 32 + ((((j >> 2) ^ (ee & 7)) << 2) | (j & 3))] = Wi[row * 512 + ee];
  }
  if (tid < 64) {
    int tg = t0 + tid;
    int pos = dir ? (sl - 1 - tg) : tg;
    pos = min(max(pos, 0), 511);
    tokS[tid] = sentence[b * 512 + pos];
  }
  __syncthreads();

  const int lane = tid & 63, w = tid >> 6;
  const int es = lane >> 3, tl8 = lane & 7;
  const int tile = w * 8 + tl8;
  const int jt = tile & 3, rt = tile >> 2;
  const int rr = tid & 63, seg = tid >> 6;

  float acc[8][8];
#pragma unroll
  for (int a = 0; a < 8; ++a)
#pragma unroll
    for (int b2 = 0; b2 < 8; ++b2) acc[a][b2] = 0.f;

  const int mytok = tokS[rr];
  float4 vb[2][8];
  {
    const float* src = embed + (size_t)mytok * 512 + seg * 32;
#pragma unroll
    for (int q = 0; q < 8; ++q) vb[0][q] = *(const float4*)(src + q * 4);
  }
  const int rq = rr >> 2, rl = rr & 3;
  const float* wp0b = wiS + (((jt * 2) ^ es) << 2) + es * 32;
  const float* wp1b = wiS + (((jt * 2 + 1) ^ es) << 2) + es * 32;
  const float* ep0 = embS + es * 64 + ((((rt * 2) ^ es)) << 2);
  const float* ep1 = embS + es * 64 + ((((rt * 2 + 1) ^ es)) << 2);

#pragma unroll
  for (int kk = 0; kk < 4; ++kk) {
    if (kk) __syncthreads();
#pragma unroll
    for (int q = 0; q < 8; ++q) {
      const int el = seg * 32 + q * 4;
      const float4 v = vb[kk & 1][q];
      embS[(el + 0) * 64 + (((rq ^ ((el + 0) & 7)) << 2) | rl)] = v.x;
      embS[(el + 1) * 64 + (((rq ^ ((el + 1) & 7)) << 2) | rl)] = v.y;
      embS[(el + 2) * 64 + (((rq ^ ((el + 2) & 7)) << 2) | rl)] = v.z;
      embS[(el + 3) * 64 + (((rq ^ ((el + 3) & 7)) << 2) | rl)] = v.w;
    }
    if (kk < 3) {
      const float* src = embed + (size_t)mytok * 512 + (kk + 1) * 128 + seg * 32;
#pragma unroll
      for (int q = 0; q < 8; ++q) vb[(kk + 1) & 1][q] = *(const float4*)(src + q * 4);
    }
    __syncthreads();
    const float* wp0 = wp0b + kk * 128 * 32;
    const float* wp1 = wp1b + kk * 128 * 32;
#pragma unroll
    for (int i = 0; i < 16; ++i) {
      const float4 w0 = *(const float4*)(wp0 + i * 256);
      const float4 w1 = *(const float4*)(wp1 + i * 256);
      const float4 x0 = *(const float4*)(ep0 + i * 512);
      const float4 x1 = *(const float4*)(ep1 + i * 512);
      float wv[8] = {w0.x, w0.y, w0.z, w0.w, w1.x, w1.y, w1.z, w1.w};
      float xv[8] = {x0.x, x0.y, x0.z, x0.w, x1.x, x1.y, x1.z, x1.w};
#pragma unroll
      for (int a = 0; a < 8; ++a)
#pragma unroll
        for (int b2 = 0; b2 < 8; ++b2) acc[a][b2] = fmaf(wv[a], xv[b2], acc[a][b2]);
    }
  }

  const bool hi1 = (lane & 8) != 0;
  float r1[4][8];
#pragma unroll
  for (int a = 0; a < 4; ++a)
#pragma unroll
    for (int b2 = 0; b2 < 8; ++b2) {
      float sendv = hi1 ? acc[a][b2] : acc[a + 4][b2];
      float keepv = hi1 ? acc[a + 4][b2] : acc[a][b2];
      r1[a][b2] = keepv + __shfl_xor(sendv, 8, 64);
    }
  const bool hi2 = (lane & 16) != 0;
  float r2[4][4];
#pragma unroll
  for (int a = 0; a < 4; ++a)
#pragma unroll
    for (int b2 = 0; b2 < 4; ++b2) {
      float sendv = hi2 ? r1[a][b2] : r1[a][b2 + 4];
      float keepv = hi2 ? r1[a][b2 + 4] : r1[a][b2];
      r2[a][b2] = keepv + __shfl_xor(sendv, 16, 64);
    }
  const bool hi3 = (lane & 32) != 0;
  float r3[2][4];
#pragma unroll
  for (int a = 0; a < 2; ++a)
#pragma unroll
    for (int b2 = 0; b2 < 4; ++b2) {
      float sendv = hi3 ? r2[a][b2] : r2[a + 2][b2];
      float keepv = hi3 ? r2[a + 2][b2] : r2[a][b2];
      r3[a][b2] = keepv + __shfl_xor(sendv, 32, 64);
    }
  const int ab1 = hi1 ? 4 : 0, bb = hi2 ? 4 : 0, ab2 = hi3 ? 2 : 0;
  const size_t base = (size_t)(ut * 4 + ct) * (TPH * 1024) + (size_t)cc * 32;
#pragma unroll
  for (int a = 0; a < 2; ++a)
#pragma unroll
    for (int b2 = 0; b2 < 4; ++b2) {
      int tau = rt * 8 + bb + b2;
      if (t0 + tau < sl)
        xp[base + (size_t)tau * 1024 + (jt * 8 + ab1 + ab2 + a)] = r3[a][b2];
    }
}

// ---------------- LSTM recurrent phase (cooperative, 256 WGs) ----------------
__global__ __launch_bounds__(BLK, 1) void lstm_phase(
    int phase, const int* __restrict__ seq_lens, const float* __restrict__ Wh_f,
    const float* __restrict__ Wh_b, const float* __restrict__ b_f,
    const float* __restrict__ b_b, const float* __restrict__ xp,
    float* __restrict__ hfull, float* __restrict__ cbuf, unsigned* __restrict__ bar) {
  extern __shared__ float sm[];
  float* wS = sm + LW_OFF;
  float* hS = sm + LH_OFF;
  float* gS = sm + LG_OFF;
  float* xpS = sm + LXP_OFF;
  float* cstS = sm + LCS_OFF;
  float* biasS = sm + LBI_OFF;
  int* slS = (int*)(sm + LSL_OFF);
  int* mslS = (int*)(sm + LMX_OFF);

  const int tid = threadIdx.x;
  const int bid = blockIdx.x;
  const int ut = bid & 63, ct = bid >> 6;
  const int u0 = ut * 8, ch0 = ct * 32, dir = ct >> 1;
  const int sub = ut >> 3;
  const float* Wh = dir ? Wh_b : Wh_f;
  const float* bb = dir ? b_b : b_f;

  if (tid < 32) slS[tid] = seq_lens[((ct & 1) << 5) + tid];
  __syncthreads();
  if (tid == 0) {
    int m = 0;
    for (int c = 0; c < 32; ++c) m = max(m, slS[c]);
    *mslS = m;
  }
  __syncthreads();
  const int gmax = *mslS;
  const int t0 = phase * TPH;
  if (t0 >= gmax) return;  // group-uniform exit

  for (int j = 0; j < 32; ++j) {
    int row = (j >> 3) * 512 + u0 + (j & 7);
    for (int ee = tid; ee < 512; ee += BLK)
      wS[ee * 32 + ((((j >> 2) ^ (ee & 7)) << 2) | (j & 3))] = Wh[row * 512 + ee];
  }
  if (tid < 32) biasS[tid] = bb[(tid >> 3) * 512 + u0 + (tid & 7)];
  cstS[tid] = cbuf[bid * 256 + tid];

  const int lane = tid & 63, w = tid >> 6;
  const int tp = lane & 15, jt = tp & 3, ct2 = tp >> 2;
  const int es = w * 4 + (lane >> 4);
  const int esw = es & 7;
  const int nst = min(TPH, gmax - t0);

  const float* wpA = wS + es * 32 + (((jt * 2) ^ esw) << 2);
  const float* wpB = wS + es * 32 + (((jt * 2 + 1) ^ esw) << 2);
  const float* hpA = hS + es * 32 + (((ct2 * 2) ^ esw) << 2);
  const float* hpB = hS + es * 32 + (((ct2 * 2 + 1) ^ esw) << 2);

  // prologue: stage xp tile 0 into LDS, prefetch tile 1
  const size_t xbase = (size_t)(ut * 4 + ct) * (TPH * 1024);
  {
    float4 x0 = *(const float4*)(xp + xbase + tid * 4);
    int c = tid >> 3, j4 = tid & 7;
    float* d = xpS + c * 33 + j4 * 4;
    d[0] = x0.x; d[1] = x0.y; d[2] = x0.z; d[3] = x0.w;
  }
  float4 xr;
  if (nst > 1) xr = *(const float4*)(xp + xbase + 1024 + tid * 4);

  for (int tl = 0; tl < nst; ++tl) {
    const int t = t0 + tl;
    const float* hcur = hfull + (size_t)t * 65536;
    float* hnxt = hfull + (size_t)(t + 1) * 65536;

    // [A] bulk-stage h(t) slice -> LDS (swizzled)
#pragma unroll
    for (int it = 0; it < 16; ++it) {
      int u = it * 32 + (tid >> 3), q = tid & 7;
      float4 hv = *(const float4*)(hcur + u * 128 + ch0 + q * 4);
      *(float4*)(hS + u * 32 + ((q ^ (u & 7)) << 2)) = hv;
    }
    __syncthreads();

    // [B] 32x32x512 matmul: 8x8 register tile
    float acc[8][8];
#pragma unroll
    for (int a = 0; a < 8; ++a)
#pragma unroll
      for (int b2 = 0; b2 < 8; ++b2) acc[a][b2] = 0.f;
    for (int io = 0; io < 4; ++io) {
#pragma unroll
      for (int ii = 0; ii < 8; ++ii) {
        const int off = (io * 8 + ii) * 512;
        const float4 w0 = *(const float4*)(wpA + off);
        const float4 w1 = *(const float4*)(wpB + off);
        const float4 x0 = *(const float4*)(hpA + off);
        const float4 x1 = *(const float4*)(hpB + off);
        float wv[8] = {w0.x, w0.y, w0.z, w0.w, w1.x, w1.y, w1.z, w1.w};
        float xv[8] = {x0.x, x0.y, x0.z, x0.w, x1.x, x1.y, x1.z, x1.w};
#pragma unroll
        for (int a = 0; a < 8; ++a)
#pragma unroll
          for (int b2 = 0; b2 < 8; ++b2) acc[a][b2] = fmaf(wv[a], xv[b2], acc[a][b2]);
      }
    }

    // in-wave butterfly reduce-scatter over es lane-bits 16,32
    const bool hi1 = (lane & 16) != 0;
    float r1[4][8];
#pragma unroll
    for (int a = 0; a < 4; ++a)
#pragma unroll
      for (int b2 = 0; b2 < 8; ++b2) {
        float sendv = hi1 ? acc[a][b2] : acc[a + 4][b2];
        float keepv = hi1 ? acc[a + 4][b2] : acc[a][b2];
        r1[a][b2] = keepv + __shfl_xor(sendv, 16, 64);
      }
    const bool hi2 = (lane & 32) != 0;
    float r2[4][4];
#pragma unroll
    for (int a = 0; a < 4; ++a)
#pragma unroll
      for (int b2 = 0; b2 < 4; ++b2) {
        float sendv = hi2 ? r1[a][b2] : r1[a][b2 + 4];
        float keepv = hi2 ? r1[a][b2 + 4] : r1[a][b2];
        r2[a][b2] = keepv + __shfl_xor(sendv, 32, 64);
      }
    const int ab = hi1 ? 4 : 0, bbs = hi2 ? 4 : 0;
#pragma unroll
    for (int a = 0; a < 4; ++a) {
      float4 v = make_float4(r2[a][0], r2[a][1], r2[a][2], r2[a][3]);
      *(float4*)(gS + w * 1024 + (jt * 8 + ab + a) * 32 + ct2 * 8 + bbs) = v;
    }
    __syncthreads();

    // [C] epilogue: combine 4 wave-partials + xp + bias -> gates -> c,h
    {
      const int uu = tid >> 5, c = tid & 31;
      const int slc = slS[c];
      float s0 = 0.f, s1 = 0.f, s2 = 0.f, s3 = 0.f;
#pragma unroll
      for (int w2 = 0; w2 < 4; ++w2) {
        const float* gp = gS + w2 * 1024 + uu * 32 + c;
        s0 += gp[0];
        s1 += gp[256];
        s2 += gp[512];
        s3 += gp[768];
      }
      const bool xvalid = (t < slc);
      float x0 = xvalid ? xpS[c * 33 + uu] : 0.f;
      float x1 = xvalid ? xpS[c * 33 + 8 + uu] : 0.f;
      float x2 = xvalid ? xpS[c * 33 + 16 + uu] : 0.f;
      float x3 = xvalid ? xpS[c * 33 + 24 + uu] : 0.f;
      float iv = s0 + x0 + biasS[uu];
      float fv = s1 + x1 + biasS[8 + uu];
      float gv = s2 + x2 + biasS[16 + uu];
      float ov = s3 + x3 + biasS[24 + uu];
      float cn = sigm(fv) * cstS[uu * 32 + c] + sigm(iv) * tanhf(gv);
      float hn = sigm(ov) * tanhf(cn);
      cstS[uu * 32 + c] = cn;
      hnxt[(u0 + uu) * 128 + ch0 + c] = hn;  // single history store
    }
    __syncthreads();

    // stage xp for step t+1 (xpS free now), prefetch t+2
    if (tl + 1 < nst) {
      int c = tid >> 3, j4 = tid & 7;
      float* d = xpS + c * 33 + j4 * 4;
      d[0] = xr.x; d[1] = xr.y; d[2] = xr.z; d[3] = xr.w;
      if (tl + 2 < nst)
        xr = *(const float4*)(xp + xbase + (size_t)(tl + 2) * 1024 + tid * 4);
    }

    gbar_ct(bar, ct, sub, (unsigned)(t + 1));
  }
  cbuf[bid * 256 + tid] = cstS[tid];
}

// ---------------- feats += h(t) @ W_out-slice (deterministic: 2 commutative adds) ----------------
__global__ __launch_bounds__(256, 1) void feats_kernel(
    const int* __restrict__ seq_lens, const float* __restrict__ W_out,
    const float* __restrict__ hfull, float* __restrict__ featsF) {
  extern __shared__ float fs[];
  float* wL = fs + FK_W_OFF;
  float* hL = fs + FK_H_OFF;
  int* slL = (int*)(fs + FK_SL_OFF);
  const int tid = threadIdx.x;
  const int t = blockIdx.x, ct = blockIdx.y;
  const int dir = ct >> 1, half = ct & 1;
  if (tid < 32) slL[tid] = seq_lens[(half << 5) + tid];
  __syncthreads();
  if (t >= slL[0]) return;  // seq_lens sorted desc -> slL[0] is group max
  for (int i = tid; i < 6144; i += 256) {
    int k = i >> 9, u = i & 511;
    wL[k * 520 + u] = W_out[k * 1024 + dir * 512 + u];
  }
  const size_t slot = (size_t)(t + 1) * 65536 + ct * 32;
#pragma unroll
  for (int it = 0; it < 16; ++it) {
    int u = it * 32 + (tid >> 3), c4 = (tid & 7) * 4;
    float4 v = *(const float4*)(hfull + slot + (size_t)u * 128 + c4);
    hL[u * 33 + c4] = v.x;
    hL[u * 33 + c4 + 1] = v.y;
    hL[u * 33 + c4 + 2] = v.z;
    hL[u * 33 + c4 + 3] = v.w;
  }
  __syncthreads();
  if (tid < 192) {
    const int kk = tid >> 5, c = tid & 31;
    const int sl = slL[c];
    float a0 = 0.f, a1 = 0.f;
    for (int u = 0; u < 512; u += 4) {
#pragma unroll
      for (int q = 0; q < 4; ++q) {
        float h = hL[(u + q) * 33 + c];
        a0 = fmaf(h, wL[kk * 520 + u + q], a0);
        a1 = fmaf(h, wL[(kk + 6) * 520 + u + q], a1);
      }
    }
    if (t < sl) {
      int p = dir ? (sl - 1 - t) : t;
      int b = (half << 5) + c;
      atomicAdd(&featsF[((size_t)b * 512 + p) * 12 + kk], a0);
      atomicAdd(&featsF[((size_t)b * 512 + p) * 12 + kk + 6], a1);
    }
  }
}

// ---------------- viterbi: 64 blocks (one b each), fv replicated in registers ----------------
__global__ __launch_bounds__(64) void viterbi2(
    const int* __restrict__ seq_lens, const float* __restrict__ b_out,
    const float* __restrict__ transitions, const float* __restrict__ featsF,
    unsigned char* __restrict__ bps, float* __restrict__ out) {
  __shared__ unsigned char tagB[512];
  const int b = blockIdx.x;
  const int lane = threadIdx.x;
  const int k = lane < 12 ? lane : 0;
  const int sl = seq_lens[b];
  float trow[12];
#pragma unroll
  for (int p = 0; p < 12; ++p) trow[p] = transitions[k * 12 + p];
  const float bo = b_out[k];
  float fvv[12];
#pragma unroll
  for (int p = 0; p < 12; ++p) fvv[p] = (p == START_TAG) ? 0.f : -10000.f;
  const float* fbase = featsF + (size_t)b * 512 * 12;
  for (int t = 0; t < TSEQ; ++t) {
    float best = fvv[0] + trow[0];
    int arg = 0;
#pragma unroll
    for (int p = 1; p < 12; ++p) {
      float v = fvv[p] + trow[p];
      if (v > best) { best = v; arg = p; }
    }
    const bool m = t < sl;
    float feat = fbase[t * 12 + k] + bo;
    float nv = m ? (best + feat) : fvv[k];
    int bpv = m ? arg : k;
    if (lane < 12) bps[((size_t)t * 64 + b) * 12 + lane] = (unsigned char)bpv;
#pragma unroll
    for (int p = 0; p < 12; ++p) fvv[p] = __shfl(nv, p, 64);
  }
  __syncthreads();
  if (lane == 0) {
    float best = fvv[0] + transitions[STOP_TAG * 12 + 0];
    int arg = 0;
    for (int kk = 1; kk < 12; ++kk) {
      float v = fvv[kk] + transitions[STOP_TAG * 12 + kk];
      if (v > best) { best = v; arg = kk; }
    }
    out[b] = best;
    int tag = arg;
    const uint32_t* rowp = (const uint32_t*)bps;
    uint32_t r0, r1, r2;
    {
      size_t off = ((size_t)511 * 64 + b) * 3;
      r0 = rowp[off]; r1 = rowp[off + 1]; r2 = rowp[off + 2];
    }
    for (int t = 511; t >= 0; --t) {
      uint32_t n0 = 0, n1 = 0, n2 = 0;
      if (t > 0) {
        size_t off = ((size_t)(t - 1) * 64 + b) * 3;
        n0 = rowp[off]; n1 = rowp[off + 1]; n2 = rowp[off + 2];
      }
      tagB[t] = (unsigned char)tag;
      uint32_t sel = (tag < 4) ? (r0 >> (tag * 8))
                   : (tag < 8) ? (r1 >> ((tag - 4) * 8))
                               : (r2 >> ((tag - 8) * 8));
      tag = (int)(sel & 0xffu);
      r0 = n0; r1 = n1; r2 = n2;
    }
  }
  __syncthreads();
  for (int t = lane; t < 512; t += 64) out[64 + (size_t)b * 512 + t] = (float)tagB[t];
}

extern "C" void kernel_launch(void* const* d_in, const int* in_sizes, int n_in,
                              void* d_out, int out_size, void* d_ws, size_t ws_size,
                              hipStream_t stream) {
  (void)in_sizes; (void)n_in; (void)out_size; (void)ws_size;
  const int* sentence = (const int*)d_in[0];
  const int* seq_lens = (const int*)d_in[1];
  const float* embed = (const float*)d_in[2];
  const float* Wi_f = (const float*)d_in[3];
  const float* Wh_f = (const float*)d_in[4];
  const float* b_f = (const float*)d_in[5];
  const float* Wi_b = (const float*)d_in[6];
  const float* Wh_b = (const float*)d_in[7];
  const float* b_b = (const float*)d_in[8];
  const float* h0 = (const float*)d_in[9];
  const float* c0 = (const float*)d_in[10];
  const float* W_out = (const float*)d_in[11];
  const float* b_out = (const float*)d_in[12];
  const float* trans = (const float*)d_in[13];

  char* ws = (char*)d_ws;
  unsigned* bar = (unsigned*)ws;
  float* featsF = (float*)(ws + FEATS_OFF);
  float* cbuf = (float*)(ws + CBUF_OFF);
  unsigned char* bps = (unsigned char*)(ws + BPS_OFF);
  float* xpw = (float*)(ws + XP_OFF);
  float* hfull = (float*)(ws + HFULL_OFF);

  hipMemsetAsync(d_ws, 0, FEATS_OFF + FEATS_BYTES, stream);  // bar + feats

  hipFuncSetAttribute((const void*)lstm_phase,
                      hipFuncAttributeMaxDynamicSharedMemorySize, LSTM_SMEM_BYTES);
  hipFuncSetAttribute((const void*)pre_gemm,
                      hipFuncAttributeMaxDynamicSharedMemorySize, PRE_SMEM_BYTES);
  hipFuncSetAttribute((const void*)feats_kernel,
                      hipFuncAttributeMaxDynamicSharedMemorySize, FK_SMEM_BYTES);

  init_state<<<dim3(512), dim3(256), 0, stream>>>(h0, c0, hfull, cbuf);

  for (int p = 0; p < NPH; ++p) {
    pre_gemm<<<dim3(128, 64), dim3(BLK), PRE_SMEM_BYTES, stream>>>(
        p, sentence, seq_lens, embed, Wi_f, Wi_b, xpw);
    int pv = p;
    void* kargs[] = {(void*)&pv,   (void*)&seq_lens, (void*)&Wh_f, (void*)&Wh_b,
                     (void*)&b_f,  (void*)&b_b,      (void*)&xpw,  (void*)&hfull,
                     (void*)&cbuf, (void*)&bar};
    hipLaunchCooperativeKernel((const void*)lstm_phase, dim3(NWG), dim3(BLK), kargs,
                               LSTM_SMEM_BYTES, stream);
  }
  feats_kernel<<<dim3(TSEQ, 4), dim3(256), FK_SMEM_BYTES, stream>>>(seq_lens, W_out,
                                                                    hfull, featsF);
  viterbi2<<<dim3(64), dim3(64), 0, stream>>>(seq_lens, b_out, trans, featsF, bps,
                                              (float*)d_out);
}

// Round 4
// 8594.378 us; speedup vs baseline: 1.1922x; 1.1622x over previous
//
#include <hip/hip_runtime.h>
#include <stdint.h>

// ---------------- problem constants ----------------
#define BSZ 64
#define TSEQ 512
#define KTAG 12
#define START_TAG 10
#define STOP_TAG 11

#define TPH 64   // timesteps per phase
#define NPH 8    // phases (TPH*NPH == TSEQ)
#define NWG 256
#define BLK 256

#define FIX_SCALE 4294967296.0
#define FIX_INV 2.3283064365386963e-10

// ---------------- workspace layout (bytes) ----------------
// bar: per ct (4 groups): flag at [ct*64], counter at [ct*64+16]
#define BAR_BYTES 4096
#define FEATS_OFF BAR_BYTES
#define FEATS_BYTES (BSZ * TSEQ * KTAG * 8)         // 3145728 (u64 fixed-point)
#define HBUF_OFF (FEATS_OFF + FEATS_BYTES)          // 3149824
#define HBUF_BYTES (2 * 512 * 128 * 4)              // 524288 (ping-pong h [u][ch])
#define CBUF_OFF (HBUF_OFF + HBUF_BYTES)            // 3674112
#define CBUF_BYTES (NWG * 256 * 4)                  // 262144
#define BPS_OFF (CBUF_OFF + CBUF_BYTES)             // 3936256
#define BPS_BYTES (TSEQ * BSZ * KTAG)               // 393216
#define XP_OFF (BPS_OFF + BPS_BYTES)                // 4329472
#define XP_BYTES (64 * 4 * TPH * 32 * 32 * 4)       // 67108864; total ~71.5 MB

// ---------------- LSTM phase kernel LDS (float offsets) ----------------
#define LW_OFF 0        // 16384: Wh slice [e 512][32 j] quad-XOR swizzled
#define LH_OFF 16384    // 16384: h slice  [e 512][32 c] quad-XOR swizzled
#define LG_OFF 32768    // 4096 : per-wave partial gates [4][32 j][32 c]
#define LXP_OFF 36864   // 1056 : xp tile [32 c][33]
#define LHL_OFF 37920   // 256  : h local [8 uu][32 c]
#define LCS_OFF 38176   // 256  : c-state [8 uu][32 c]
#define LBI_OFF 38432   // 32   : bias
#define LWO_OFF 38464   // 96   : W_out slice [12 k][8 uu]
#define LSL_OFF 38560   // 32 ints: seq lens
#define LMX_OFF 38592   // 1 int : group max seq len
#define LSTM_SMEM_FLOATS 38596
#define LSTM_SMEM_BYTES (LSTM_SMEM_FLOATS * 4)      // 154384 < 160 KiB

// ---------------- pre-GEMM kernel LDS ----------------
#define PW_OFF 0        // 16384: Wi slice [e 512][32 j] swizzled
#define PE_OFF 16384    // 8192 : emb chunk [e 128][64 r] swizzled
#define PT_OFF 24576    // 64 ints: tokens
#define PRE_SMEM_FLOATS 24640
#define PRE_SMEM_BYTES (PRE_SMEM_FLOATS * 4)        // 98560

__device__ __forceinline__ float sigm(float x) { return 1.f / (1.f + expf(-x)); }

// per-ct barrier over 64 WGs: flat counter + single broadcast flag (round-1 proven)
__device__ __forceinline__ void gbar64(unsigned* bar, int g, unsigned epoch) {
  __syncthreads();
  if (threadIdx.x == 0) {
    __builtin_amdgcn_fence(__ATOMIC_RELEASE, "agent");
    unsigned o = __hip_atomic_fetch_add(&bar[g * 64 + 16], 1u, __ATOMIC_RELAXED,
                                        __HIP_MEMORY_SCOPE_AGENT);
    if (o == epoch * 64u - 1u) {
      __builtin_amdgcn_fence(__ATOMIC_ACQUIRE, "agent");
      __hip_atomic_store(&bar[g * 64], epoch, __ATOMIC_RELAXED, __HIP_MEMORY_SCOPE_AGENT);
    } else {
      while (__hip_atomic_load(&bar[g * 64], __ATOMIC_RELAXED, __HIP_MEMORY_SCOPE_AGENT) <
             epoch) {}
      __builtin_amdgcn_fence(__ATOMIC_ACQUIRE, "agent");
    }
  }
  __syncthreads();
}

// ---------------- init: h0 -> hbuf slot 0, c0 -> cbuf ----------------
__global__ void init_state(const float* __restrict__ h0, const float* __restrict__ c0,
                           float* __restrict__ hbuf, float* __restrict__ cbuf) {
  int i = blockIdx.x * 256 + threadIdx.x;
  if (i < 65536) {
    int u = i >> 7, ch = i & 127;
    int ct = ch >> 5, c = ch & 31;
    int dir = ct >> 1, b = ((ct & 1) << 5) + c;
    hbuf[i] = h0[(dir * 64 + b) * 512 + u];
  } else {
    int j = i - 65536;
    int wg = j >> 8, r = j & 255;
    int ct = wg >> 6, ut = wg & 63;
    int uu = r >> 5, c = r & 31;
    int dir = ct >> 1, b = ((ct & 1) << 5) + c;
    cbuf[j] = c0[(dir * 64 + b) * 512 + ut * 8 + uu];
  }
}

// ---------------- pre-GEMM: one WG = (dir,ut) x 8 batch rows; Wi staged once ----------------
// xp[ut][ct][taul][c][j] = emb(b, pos(tau)) @ Wi_slice
__global__ __launch_bounds__(256, 1) void pre_gemm(
    int phase, const int* __restrict__ sentence, const int* __restrict__ seq_lens,
    const float* __restrict__ embed, const float* __restrict__ Wi_f,
    const float* __restrict__ Wi_b, float* __restrict__ xp) {
  extern __shared__ float sm[];
  float* wiS = sm + PW_OFF;
  float* embS = sm + PE_OFF;
  int* tokS = (int*)(sm + PT_OFF);

  const int tid = threadIdx.x;
  const int dirut = blockIdx.x;            // 128
  const int dir = dirut >> 6, ut = dirut & 63;
  const int yo = blockIdx.y;               // 8 octets of batch rows
  const int t0 = phase * TPH;
  if (t0 >= seq_lens[yo * 8]) return;      // sorted desc -> whole octet masked
  const int u0 = ut * 8;
  const float* Wi = dir ? Wi_b : Wi_f;

  // stage Wi slice ONCE for all 8 batch rows
  for (int j = 0; j < 32; ++j) {
    int row = (j >> 3) * 512 + u0 + (j & 7);
    for (int ee = tid; ee < 512; ee += BLK)
      wiS[ee * 32 + ((((j >> 2) ^ (ee & 7)) << 2) | (j & 3))] = Wi[row * 512 + ee];
  }

  const int lane = tid & 63, w = tid >> 6;
  const int es = lane >> 3, tl8 = lane & 7;
  const int tile = w * 8 + tl8;
  const int jt = tile & 3, rt = tile >> 2;
  const int rr = tid & 63, seg = tid >> 6;
  const int rq = rr >> 2, rl = rr & 3;
  const float* wp0b = wiS + (((jt * 2) ^ es) << 2) + es * 32;
  const float* wp1b = wiS + (((jt * 2 + 1) ^ es) << 2) + es * 32;
  const float* ep0 = embS + es * 64 + (((rt * 2) ^ es) << 2);
  const float* ep1 = embS + es * 64 + (((rt * 2 + 1) ^ es) << 2);
  const bool hi1 = (lane & 8) != 0;
  const bool hi2 = (lane & 16) != 0;
  const bool hi3 = (lane & 32) != 0;
  const int ab1 = hi1 ? 4 : 0, bb = hi2 ? 4 : 0, ab2 = hi3 ? 2 : 0;

  for (int ib = 0; ib < 8; ++ib) {
    const int b = yo * 8 + ib;
    const int sl = seq_lens[b];
    if (t0 >= sl) break;                   // sorted desc within octet
    const int ct = dir * 2 + (b >> 5);
    const int cc = b & 31;

    __syncthreads();                       // prior iter's embS/tokS reads done
    if (tid < 64) {
      int tg = t0 + tid;
      int pos = dir ? (sl - 1 - tg) : tg;
      pos = min(max(pos, 0), 511);
      tokS[tid] = sentence[b * 512 + pos];
    }
    __syncthreads();

    const int mytok = tokS[rr];
    float4 vb[2][8];
    {
      const float* src = embed + (size_t)mytok * 512 + seg * 32;
#pragma unroll
      for (int q = 0; q < 8; ++q) vb[0][q] = *(const float4*)(src + q * 4);
    }
    float acc[8][8];
#pragma unroll
    for (int a = 0; a < 8; ++a)
#pragma unroll
      for (int b2 = 0; b2 < 8; ++b2) acc[a][b2] = 0.f;

#pragma unroll
    for (int kk = 0; kk < 4; ++kk) {
      if (kk) __syncthreads();
#pragma unroll
      for (int q = 0; q < 8; ++q) {
        const int el = seg * 32 + q * 4;
        const float4 v = vb[kk & 1][q];
        embS[(el + 0) * 64 + (((rq ^ ((el + 0) & 7)) << 2) | rl)] = v.x;
        embS[(el + 1) * 64 + (((rq ^ ((el + 1) & 7)) << 2) | rl)] = v.y;
        embS[(el + 2) * 64 + (((rq ^ ((el + 2) & 7)) << 2) | rl)] = v.z;
        embS[(el + 3) * 64 + (((rq ^ ((el + 3) & 7)) << 2) | rl)] = v.w;
      }
      if (kk < 3) {
        const float* src = embed + (size_t)mytok * 512 + (kk + 1) * 128 + seg * 32;
#pragma unroll
        for (int q = 0; q < 8; ++q) vb[(kk + 1) & 1][q] = *(const float4*)(src + q * 4);
      }
      __syncthreads();
      const float* wp0 = wp0b + kk * 128 * 32;
      const float* wp1 = wp1b + kk * 128 * 32;
#pragma unroll
      for (int i = 0; i < 16; ++i) {
        const float4 w0 = *(const float4*)(wp0 + i * 256);
        const float4 w1 = *(const float4*)(wp1 + i * 256);
        const float4 x0 = *(const float4*)(ep0 + i * 512);
        const float4 x1 = *(const float4*)(ep1 + i * 512);
        float wv[8] = {w0.x, w0.y, w0.z, w0.w, w1.x, w1.y, w1.z, w1.w};
        float xv[8] = {x0.x, x0.y, x0.z, x0.w, x1.x, x1.y, x1.z, x1.w};
#pragma unroll
        for (int a = 0; a < 8; ++a)
#pragma unroll
          for (int b2 = 0; b2 < 8; ++b2) acc[a][b2] = fmaf(wv[a], xv[b2], acc[a][b2]);
      }
    }

    // butterfly reduce-scatter over es lane-bits 8,16,32
    float r1[4][8];
#pragma unroll
    for (int a = 0; a < 4; ++a)
#pragma unroll
      for (int b2 = 0; b2 < 8; ++b2) {
        float sendv = hi1 ? acc[a][b2] : acc[a + 4][b2];
        float keepv = hi1 ? acc[a + 4][b2] : acc[a][b2];
        r1[a][b2] = keepv + __shfl_xor(sendv, 8, 64);
      }
    float r2[4][4];
#pragma unroll
    for (int a = 0; a < 4; ++a)
#pragma unroll
      for (int b2 = 0; b2 < 4; ++b2) {
        float sendv = hi2 ? r1[a][b2] : r1[a][b2 + 4];
        float keepv = hi2 ? r1[a][b2 + 4] : r1[a][b2];
        r2[a][b2] = keepv + __shfl_xor(sendv, 16, 64);
      }
    float r3[2][4];
#pragma unroll
    for (int a = 0; a < 2; ++a)
#pragma unroll
      for (int b2 = 0; b2 < 4; ++b2) {
        float sendv = hi3 ? r2[a][b2] : r2[a + 2][b2];
        float keepv = hi3 ? r2[a + 2][b2] : r2[a][b2];
        r3[a][b2] = keepv + __shfl_xor(sendv, 32, 64);
      }
    const size_t base = (size_t)(ut * 4 + ct) * (TPH * 1024) + (size_t)cc * 32;
#pragma unroll
    for (int a = 0; a < 2; ++a)
#pragma unroll
      for (int b2 = 0; b2 < 4; ++b2) {
        int tau = rt * 8 + bb + b2;
        if (t0 + tau < sl)
          xp[base + (size_t)tau * 1024 + (jt * 8 + ab1 + ab2 + a)] = r3[a][b2];
      }
  }
}

// ---------------- LSTM recurrent phase (cooperative, 256 WGs) — round-1 proven config ----------------
__global__ __launch_bounds__(BLK, 1) void lstm_phase(
    int phase, const int* __restrict__ seq_lens, const float* __restrict__ Wh_f,
    const float* __restrict__ Wh_b, const float* __restrict__ b_f,
    const float* __restrict__ b_b, const float* __restrict__ W_out,
    const float* __restrict__ xp, float* __restrict__ hbuf, float* __restrict__ cbuf,
    unsigned long long* __restrict__ featsFix, unsigned* __restrict__ bar) {
  extern __shared__ float sm[];
  float* wS = sm + LW_OFF;
  float* hS = sm + LH_OFF;
  float* gS = sm + LG_OFF;
  float* xpS = sm + LXP_OFF;
  float* hlS = sm + LHL_OFF;
  float* cstS = sm + LCS_OFF;
  float* biasS = sm + LBI_OFF;
  float* woutS = sm + LWO_OFF;
  int* slS = (int*)(sm + LSL_OFF);
  int* mslS = (int*)(sm + LMX_OFF);

  const int tid = threadIdx.x;
  const int bid = blockIdx.x;
  const int ut = bid & 63, ct = bid >> 6;
  const int u0 = ut * 8, ch0 = ct * 32, dir = ct >> 1;
  const float* Wh = dir ? Wh_b : Wh_f;
  const float* bb = dir ? b_b : b_f;

  if (tid < 32) slS[tid] = seq_lens[((ct & 1) << 5) + tid];
  __syncthreads();
  if (tid == 0) {
    int m = 0;
    for (int c = 0; c < 32; ++c) m = max(m, slS[c]);
    *mslS = m;
  }
  __syncthreads();
  const int gmax = *mslS;
  const int t0 = phase * TPH;
  if (t0 >= gmax) return;  // group-uniform exit

  for (int j = 0; j < 32; ++j) {
    int row = (j >> 3) * 512 + u0 + (j & 7);
    for (int ee = tid; ee < 512; ee += BLK)
      wS[ee * 32 + ((((j >> 2) ^ (ee & 7)) << 2) | (j & 3))] = Wh[row * 512 + ee];
  }
  if (tid < 96) woutS[tid] = W_out[(tid >> 3) * 1024 + dir * 512 + u0 + (tid & 7)];
  if (tid < 32) biasS[tid] = bb[(tid >> 3) * 512 + u0 + (tid & 7)];
  cstS[tid] = cbuf[bid * 256 + tid];
  __syncthreads();

  const int lane = tid & 63, w = tid >> 6;
  const int tp = lane & 15, jt = tp & 3, ct2 = tp >> 2;
  const int es = w * 4 + (lane >> 4);
  const int esw = es & 7;
  const int nst = min(TPH, gmax - t0);

  const float* wpA = wS + es * 32 + (((jt * 2) ^ esw) << 2);
  const float* wpB = wS + es * 32 + (((jt * 2 + 1) ^ esw) << 2);
  const float* hpA = hS + es * 32 + (((ct2 * 2) ^ esw) << 2);
  const float* hpB = hS + es * 32 + (((ct2 * 2 + 1) ^ esw) << 2);

  float4 xr = *(const float4*)(xp + ((size_t)(ut * 4 + ct) * TPH + 0) * 1024 + tid * 4);

  for (int tl = 0; tl < nst; ++tl) {
    const int t = t0 + tl;
    const float* hcur = hbuf + (t & 1) * 65536;
    float* hnxt = hbuf + ((t + 1) & 1) * 65536;

    // [A] bulk-stage h slice -> LDS (swizzled); store xp regs; prefetch next xp
#pragma unroll
    for (int it = 0; it < 16; ++it) {
      int u = it * 32 + (tid >> 3), q = tid & 7;
      float4 hv = *(const float4*)(hcur + u * 128 + ch0 + q * 4);
      *(float4*)(hS + u * 32 + ((q ^ (u & 7)) << 2)) = hv;
    }
    {
      int c = tid >> 3, j4 = tid & 7;
      float* d = xpS + c * 33 + j4 * 4;
      d[0] = xr.x; d[1] = xr.y; d[2] = xr.z; d[3] = xr.w;
    }
    if (tl + 1 < nst)
      xr = *(const float4*)(xp + ((size_t)(ut * 4 + ct) * TPH + (tl + 1)) * 1024 + tid * 4);
    __syncthreads();

    // [B] 32x32x512 matmul: 8x8 register tile
    float acc[8][8];
#pragma unroll
    for (int a = 0; a < 8; ++a)
#pragma unroll
      for (int b2 = 0; b2 < 8; ++b2) acc[a][b2] = 0.f;
    for (int io = 0; io < 4; ++io) {
#pragma unroll
      for (int ii = 0; ii < 8; ++ii) {
        const int off = (io * 8 + ii) * 512;
        const float4 w0 = *(const float4*)(wpA + off);
        const float4 w1 = *(const float4*)(wpB + off);
        const float4 x0 = *(const float4*)(hpA + off);
        const float4 x1 = *(const float4*)(hpB + off);
        float wv[8] = {w0.x, w0.y, w0.z, w0.w, w1.x, w1.y, w1.z, w1.w};
        float xv[8] = {x0.x, x0.y, x0.z, x0.w, x1.x, x1.y, x1.z, x1.w};
#pragma unroll
        for (int a = 0; a < 8; ++a)
#pragma unroll
          for (int b2 = 0; b2 < 8; ++b2) acc[a][b2] = fmaf(wv[a], xv[b2], acc[a][b2]);
      }
    }

    // in-wave butterfly reduce-scatter over es lane-bits 16,32
    const bool hi1 = (lane & 16) != 0;
    float r1[4][8];
#pragma unroll
    for (int a = 0; a < 4; ++a)
#pragma unroll
      for (int b2 = 0; b2 < 8; ++b2) {
        float sendv = hi1 ? acc[a][b2] : acc[a + 4][b2];
        float keepv = hi1 ? acc[a + 4][b2] : acc[a][b2];
        r1[a][b2] = keepv + __shfl_xor(sendv, 16, 64);
      }
    const bool hi2 = (lane & 32) != 0;
    float r2[4][4];
#pragma unroll
    for (int a = 0; a < 4; ++a)
#pragma unroll
      for (int b2 = 0; b2 < 4; ++b2) {
        float sendv = hi2 ? r1[a][b2] : r1[a][b2 + 4];
        float keepv = hi2 ? r1[a][b2 + 4] : r1[a][b2];
        r2[a][b2] = keepv + __shfl_xor(sendv, 32, 64);
      }
    const int ab = hi1 ? 4 : 0, bbs = hi2 ? 4 : 0;
#pragma unroll
    for (int a = 0; a < 4; ++a) {
      float4 v = make_float4(r2[a][0], r2[a][1], r2[a][2], r2[a][3]);
      *(float4*)(gS + w * 1024 + (jt * 8 + ab + a) * 32 + ct2 * 8 + bbs) = v;
    }
    __syncthreads();

    // [C] epilogue: combine 4 wave-partials + xp + bias -> gates -> c,h
    {
      const int uu = tid >> 5, c = tid & 31;
      const int slc = slS[c];
      float s0 = 0.f, s1 = 0.f, s2 = 0.f, s3 = 0.f;
#pragma unroll
      for (int w2 = 0; w2 < 4; ++w2) {
        const float* gp = gS + w2 * 1024 + uu * 32 + c;
        s0 += gp[0];
        s1 += gp[256];
        s2 += gp[512];
        s3 += gp[768];
      }
      const bool xvalid = (t < slc);
      float x0 = xvalid ? xpS[c * 33 + uu] : 0.f;
      float x1 = xvalid ? xpS[c * 33 + 8 + uu] : 0.f;
      float x2 = xvalid ? xpS[c * 33 + 16 + uu] : 0.f;
      float x3 = xvalid ? xpS[c * 33 + 24 + uu] : 0.f;
      float iv = s0 + x0 + biasS[uu];
      float fv = s1 + x1 + biasS[8 + uu];
      float gv = s2 + x2 + biasS[16 + uu];
      float ov = s3 + x3 + biasS[24 + uu];
      float cn = sigm(fv) * cstS[uu * 32 + c] + sigm(iv) * tanhf(gv);
      float hn = sigm(ov) * tanhf(cn);
      cstS[uu * 32 + c] = cn;
      hnxt[(u0 + uu) * 128 + ch0 + c] = hn;
      hlS[uu * 32 + c] = hn;
    }
    __syncthreads();

    // feats partial: fixed-point atomics (deterministic, overlapped with barrier)
    for (int base = 0; base < 384; base += 256) {
      int idx = base + tid;
      if (idx < 384) {
        int c = idx / 12, k = idx % 12;
        int sl = slS[c];
        if (t < sl) {
          float pacc = 0.f;
#pragma unroll
          for (int uu = 0; uu < 8; ++uu) pacc += hlS[uu * 32 + c] * woutS[k * 8 + uu];
          int tt = dir ? (sl - 1 - t) : t;
          double y = (double)pacc * FIX_SCALE;
          long long q = (long long)(y + (y >= 0.0 ? 0.5 : -0.5));
          atomicAdd(&featsFix[((size_t)(((ct & 1) << 5) + c) * 512 + tt) * 12 + k],
                    (unsigned long long)q);
        }
      }
    }
    gbar64(bar, ct, (unsigned)(t + 1));
  }
  cbuf[bid * 256 + tid] = cstS[tid];
}

// ---------------- viterbi: 64 blocks (one b each), fv replicated via shfl ----------------
__global__ __launch_bounds__(64) void viterbi2(
    const int* __restrict__ seq_lens, const float* __restrict__ b_out,
    const float* __restrict__ transitions,
    const unsigned long long* __restrict__ featsFix,
    unsigned char* __restrict__ bps, float* __restrict__ out) {
  __shared__ unsigned char tagB[512];
  const int b = blockIdx.x;
  const int lane = threadIdx.x;
  const int k = lane < 12 ? lane : 0;
  const int sl = seq_lens[b];
  float trow[12];
#pragma unroll
  for (int p = 0; p < 12; ++p) trow[p] = transitions[k * 12 + p];
  const float bo = b_out[k];
  float fvv[12];
#pragma unroll
  for (int p = 0; p < 12; ++p) fvv[p] = (p == START_TAG) ? 0.f : -10000.f;
  const unsigned long long* fbase = featsFix + (size_t)b * 512 * 12;
  long long fx = (long long)fbase[k];
  for (int t = 0; t < TSEQ; ++t) {
    float best = fvv[0] + trow[0];
    int arg = 0;
#pragma unroll
    for (int p = 1; p < 12; ++p) {
      float v = fvv[p] + trow[p];
      if (v > best) { best = v; arg = p; }
    }
    float feat = (float)((double)fx * FIX_INV) + bo;
    if (t + 1 < TSEQ) fx = (long long)fbase[(t + 1) * 12 + k];
    const bool m = t < sl;
    float nv = m ? (best + feat) : fvv[k];
    int bpv = m ? arg : k;
    if (lane < 12) bps[((size_t)t * 64 + b) * 12 + lane] = (unsigned char)bpv;
#pragma unroll
    for (int p = 0; p < 12; ++p) fvv[p] = __shfl(nv, p, 64);
  }
  __syncthreads();
  if (lane == 0) {
    float best = fvv[0] + transitions[STOP_TAG * 12 + 0];
    int arg = 0;
    for (int kk = 1; kk < 12; ++kk) {
      float v = fvv[kk] + transitions[STOP_TAG * 12 + kk];
      if (v > best) { best = v; arg = kk; }
    }
    out[b] = best;
    int tag = arg;
    const uint32_t* rowp = (const uint32_t*)bps;
    uint32_t r0, r1, r2;
    {
      size_t off = ((size_t)511 * 64 + b) * 3;
      r0 = rowp[off]; r1 = rowp[off + 1]; r2 = rowp[off + 2];
    }
    for (int t = 511; t >= 0; --t) {
      uint32_t n0 = 0, n1 = 0, n2 = 0;
      if (t > 0) {
        size_t off = ((size_t)(t - 1) * 64 + b) * 3;
        n0 = rowp[off]; n1 = rowp[off + 1]; n2 = rowp[off + 2];
      }
      tagB[t] = (unsigned char)tag;
      uint32_t sel = (tag < 4) ? (r0 >> (tag * 8))
                   : (tag < 8) ? (r1 >> ((tag - 4) * 8))
                               : (r2 >> ((tag - 8) * 8));
      tag = (int)(sel & 0xffu);
      r0 = n0; r1 = n1; r2 = n2;
    }
  }
  __syncthreads();
  for (int t = lane; t < 512; t += 64) out[64 + (size_t)b * 512 + t] = (float)tagB[t];
}

extern "C" void kernel_launch(void* const* d_in, const int* in_sizes, int n_in,
                              void* d_out, int out_size, void* d_ws, size_t ws_size,
                              hipStream_t stream) {
  (void)in_sizes; (void)n_in; (void)out_size; (void)ws_size;
  const int* sentence = (const int*)d_in[0];
  const int* seq_lens = (const int*)d_in[1];
  const float* embed = (const float*)d_in[2];
  const float* Wi_f = (const float*)d_in[3];
  const float* Wh_f = (const float*)d_in[4];
  const float* b_f = (const float*)d_in[5];
  const float* Wi_b = (const float*)d_in[6];
  const float* Wh_b = (const float*)d_in[7];
  const float* b_b = (const float*)d_in[8];
  const float* h0 = (const float*)d_in[9];
  const float* c0 = (const float*)d_in[10];
  const float* W_out = (const float*)d_in[11];
  const float* b_out = (const float*)d_in[12];
  const float* trans = (const float*)d_in[13];

  char* ws = (char*)d_ws;
  unsigned* bar = (unsigned*)ws;
  unsigned long long* featsFix = (unsigned long long*)(ws + FEATS_OFF);
  float* hbuf = (float*)(ws + HBUF_OFF);
  float* cbuf = (float*)(ws + CBUF_OFF);
  unsigned char* bps = (unsigned char*)(ws + BPS_OFF);
  float* xpw = (float*)(ws + XP_OFF);

  hipMemsetAsync(d_ws, 0, FEATS_OFF + FEATS_BYTES, stream);  // bar + featsFix

  hipFuncSetAttribute((const void*)lstm_phase,
                      hipFuncAttributeMaxDynamicSharedMemorySize, LSTM_SMEM_BYTES);
  hipFuncSetAttribute((const void*)pre_gemm,
                      hipFuncAttributeMaxDynamicSharedMemorySize, PRE_SMEM_BYTES);

  init_state<<<dim3(512), dim3(256), 0, stream>>>(h0, c0, hbuf, cbuf);

  for (int p = 0; p < NPH; ++p) {
    pre_gemm<<<dim3(128, 8), dim3(BLK), PRE_SMEM_BYTES, stream>>>(
        p, sentence, seq_lens, embed, Wi_f, Wi_b, xpw);
    int pv = p;
    void* kargs[] = {(void*)&pv,    (void*)&seq_lens, (void*)&Wh_f,     (void*)&Wh_b,
                     (void*)&b_f,   (void*)&b_b,      (void*)&W_out,    (void*)&xpw,
                     (void*)&hbuf,  (void*)&cbuf,     (void*)&featsFix, (void*)&bar};
    hipLaunchCooperativeKernel((const void*)lstm_phase, dim3(NWG), dim3(BLK), kargs,
                               LSTM_SMEM_BYTES, stream);
  }
  viterbi2<<<dim3(64), dim3(64), 0, stream>>>(seq_lens, b_out, trans, featsFix, bps,
                                              (float*)d_out);
}

// Round 5
// 7135.728 us; speedup vs baseline: 1.4359x; 1.2044x over previous
//
#include <hip/hip_runtime.h>
#include <stdint.h>

// ---------------- problem constants ----------------
#define BSZ 64
#define TSEQ 512
#define KTAG 12
#define START_TAG 10
#define STOP_TAG 11

#define TPH 64   // timesteps per phase
#define NPH 8    // phases (TPH*NPH == TSEQ)
#define NWG 256
#define BLK 256

#define FIX_SCALE 4294967296.0
#define FIX_INV 2.3283064365386963e-10

typedef unsigned long long u64t;

// ---------------- workspace layout (bytes) ----------------
// bar: per ct (4 groups): flag at [ct*64], counter at [ct*64+16]
#define BAR_BYTES 4096
#define FEATS_OFF BAR_BYTES
#define FEATS_BYTES (BSZ * TSEQ * KTAG * 8)         // 3145728 (u64 fixed-point)
#define HBUF_OFF (FEATS_OFF + FEATS_BYTES)          // 3149824
#define HBUF_BYTES (2 * 512 * 128 * 4)              // 524288 (ping-pong h [u][ch])
#define CBUF_OFF (HBUF_OFF + HBUF_BYTES)            // 3674112
#define CBUF_BYTES (NWG * 256 * 4)                  // 262144
#define BPS_OFF (CBUF_OFF + CBUF_BYTES)             // 3936256
#define BPS_BYTES (TSEQ * BSZ * KTAG)               // 393216
#define XP_OFF (BPS_OFF + BPS_BYTES)                // 4329472
#define XP_BYTES (64 * 4 * TPH * 32 * 32 * 4)       // 67108864; total ~71.5 MB

// ---------------- LSTM phase kernel LDS (float offsets) ----------------
#define LW_OFF 0        // 16384: Wh slice [e 512][32 j] quad-XOR swizzled
#define LH_OFF 16384    // 16384: h slice  [e 512][32 c] quad-XOR swizzled
#define LG_OFF 32768    // 4096 : per-wave partial gates [4][32 j][32 c]
#define LXP_OFF 36864   // 1056 : xp tile [32 c][33]
#define LHL_OFF 37920   // 256  : h local [8 uu][32 c]
#define LCS_OFF 38176   // 256  : c-state [8 uu][32 c]
#define LBI_OFF 38432   // 32   : bias
#define LWO_OFF 38464   // 96   : W_out slice [12 k][8 uu]
#define LSL_OFF 38560   // 32 ints: seq lens
#define LMX_OFF 38592   // 1 int : group max seq len
#define LSTM_SMEM_FLOATS 38596
#define LSTM_SMEM_BYTES (LSTM_SMEM_FLOATS * 4)      // 154384 < 160 KiB

// ---------------- pre-GEMM kernel LDS ----------------
#define PW_OFF 0        // 16384: Wi slice [e 512][32 j] swizzled
#define PE_OFF 16384    // 8192 : emb chunk [e 128][64 r] swizzled
#define PT_OFF 24576    // 64 ints: tokens
#define PRE_SMEM_FLOATS 24640
#define PRE_SMEM_BYTES (PRE_SMEM_FLOATS * 4)        // 98560

__device__ __forceinline__ float sigm(float x) { return 1.f / (1.f + expf(-x)); }

// ---------------- init: h0 -> hbuf slot 0, c0 -> cbuf ----------------
__global__ void init_state(const float* __restrict__ h0, const float* __restrict__ c0,
                           float* __restrict__ hbuf, float* __restrict__ cbuf) {
  int i = blockIdx.x * 256 + threadIdx.x;
  if (i < 65536) {
    int u = i >> 7, ch = i & 127;
    int ct = ch >> 5, c = ch & 31;
    int dir = ct >> 1, b = ((ct & 1) << 5) + c;
    hbuf[i] = h0[(dir * 64 + b) * 512 + u];
  } else {
    int j = i - 65536;
    int wg = j >> 8, r = j & 255;
    int ct = wg >> 6, ut = wg & 63;
    int uu = r >> 5, c = r & 31;
    int dir = ct >> 1, b = ((ct & 1) << 5) + c;
    cbuf[j] = c0[(dir * 64 + b) * 512 + ut * 8 + uu];
  }
}

// ---------------- pre-GEMM: one WG = (dir,ut) x 8 batch rows; Wi staged once ----------------
// xp[ut][ct][taul][c][j] = emb(b, pos(tau)) @ Wi_slice
__global__ __launch_bounds__(256, 1) void pre_gemm(
    int phase, const int* __restrict__ sentence, const int* __restrict__ seq_lens,
    const float* __restrict__ embed, const float* __restrict__ Wi_f,
    const float* __restrict__ Wi_b, float* __restrict__ xp) {
  extern __shared__ float sm[];
  float* wiS = sm + PW_OFF;
  float* embS = sm + PE_OFF;
  int* tokS = (int*)(sm + PT_OFF);

  const int tid = threadIdx.x;
  const int dirut = blockIdx.x;            // 128
  const int dir = dirut >> 6, ut = dirut & 63;
  const int yo = blockIdx.y;               // 8 octets of batch rows
  const int t0 = phase * TPH;
  if (t0 >= seq_lens[yo * 8]) return;      // sorted desc -> whole octet masked
  const int u0 = ut * 8;
  const float* Wi = dir ? Wi_b : Wi_f;

  // stage Wi slice ONCE for all 8 batch rows
  for (int j = 0; j < 32; ++j) {
    int row = (j >> 3) * 512 + u0 + (j & 7);
    for (int ee = tid; ee < 512; ee += BLK)
      wiS[ee * 32 + ((((j >> 2) ^ (ee & 7)) << 2) | (j & 3))] = Wi[row * 512 + ee];
  }

  const int lane = tid & 63, w = tid >> 6;
  const int es = lane >> 3, tl8 = lane & 7;
  const int tile = w * 8 + tl8;
  const int jt = tile & 3, rt = tile >> 2;
  const int rr = tid & 63, seg = tid >> 6;
  const int rq = rr >> 2, rl = rr & 3;
  const float* wp0b = wiS + (((jt * 2) ^ es) << 2) + es * 32;
  const float* wp1b = wiS + (((jt * 2 + 1) ^ es) << 2) + es * 32;
  const float* ep0 = embS + es * 64 + (((rt * 2) ^ es) << 2);
  const float* ep1 = embS + es * 64 + (((rt * 2 + 1) ^ es) << 2);
  const bool hi1 = (lane & 8) != 0;
  const bool hi2 = (lane & 16) != 0;
  const bool hi3 = (lane & 32) != 0;
  const int ab1 = hi1 ? 4 : 0, bb = hi2 ? 4 : 0, ab2 = hi3 ? 2 : 0;

  for (int ib = 0; ib < 8; ++ib) {
    const int b = yo * 8 + ib;
    const int sl = seq_lens[b];
    if (t0 >= sl) break;                   // sorted desc within octet
    const int ct = dir * 2 + (b >> 5);
    const int cc = b & 31;

    __syncthreads();                       // prior iter's embS/tokS reads done
    if (tid < 64) {
      int tg = t0 + tid;
      int pos = dir ? (sl - 1 - tg) : tg;
      pos = min(max(pos, 0), 511);
      tokS[tid] = sentence[b * 512 + pos];
    }
    __syncthreads();

    const int mytok = tokS[rr];
    float4 vb[2][8];
    {
      const float* src = embed + (size_t)mytok * 512 + seg * 32;
#pragma unroll
      for (int q = 0; q < 8; ++q) vb[0][q] = *(const float4*)(src + q * 4);
    }
    float acc[8][8];
#pragma unroll
    for (int a = 0; a < 8; ++a)
#pragma unroll
      for (int b2 = 0; b2 < 8; ++b2) acc[a][b2] = 0.f;

#pragma unroll
    for (int kk = 0; kk < 4; ++kk) {
      if (kk) __syncthreads();
#pragma unroll
      for (int q = 0; q < 8; ++q) {
        const int el = seg * 32 + q * 4;
        const float4 v = vb[kk & 1][q];
        embS[(el + 0) * 64 + (((rq ^ ((el + 0) & 7)) << 2) | rl)] = v.x;
        embS[(el + 1) * 64 + (((rq ^ ((el + 1) & 7)) << 2) | rl)] = v.y;
        embS[(el + 2) * 64 + (((rq ^ ((el + 2) & 7)) << 2) | rl)] = v.z;
        embS[(el + 3) * 64 + (((rq ^ ((el + 3) & 7)) << 2) | rl)] = v.w;
      }
      if (kk < 3) {
        const float* src = embed + (size_t)mytok * 512 + (kk + 1) * 128 + seg * 32;
#pragma unroll
        for (int q = 0; q < 8; ++q) vb[(kk + 1) & 1][q] = *(const float4*)(src + q * 4);
      }
      __syncthreads();
      const float* wp0 = wp0b + kk * 128 * 32;
      const float* wp1 = wp1b + kk * 128 * 32;
#pragma unroll
      for (int i = 0; i < 16; ++i) {
        const float4 w0 = *(const float4*)(wp0 + i * 256);
        const float4 w1 = *(const float4*)(wp1 + i * 256);
        const float4 x0 = *(const float4*)(ep0 + i * 512);
        const float4 x1 = *(const float4*)(ep1 + i * 512);
        float wv[8] = {w0.x, w0.y, w0.z, w0.w, w1.x, w1.y, w1.z, w1.w};
        float xv[8] = {x0.x, x0.y, x0.z, x0.w, x1.x, x1.y, x1.z, x1.w};
#pragma unroll
        for (int a = 0; a < 8; ++a)
#pragma unroll
          for (int b2 = 0; b2 < 8; ++b2) acc[a][b2] = fmaf(wv[a], xv[b2], acc[a][b2]);
      }
    }

    // butterfly reduce-scatter over es lane-bits 8,16,32
    float r1[4][8];
#pragma unroll
    for (int a = 0; a < 4; ++a)
#pragma unroll
      for (int b2 = 0; b2 < 8; ++b2) {
        float sendv = hi1 ? acc[a][b2] : acc[a + 4][b2];
        float keepv = hi1 ? acc[a + 4][b2] : acc[a][b2];
        r1[a][b2] = keepv + __shfl_xor(sendv, 8, 64);
      }
    float r2[4][4];
#pragma unroll
    for (int a = 0; a < 4; ++a)
#pragma unroll
      for (int b2 = 0; b2 < 4; ++b2) {
        float sendv = hi2 ? r1[a][b2] : r1[a][b2 + 4];
        float keepv = hi2 ? r1[a][b2 + 4] : r1[a][b2];
        r2[a][b2] = keepv + __shfl_xor(sendv, 16, 64);
      }
    float r3[2][4];
#pragma unroll
    for (int a = 0; a < 2; ++a)
#pragma unroll
      for (int b2 = 0; b2 < 4; ++b2) {
        float sendv = hi3 ? r2[a][b2] : r2[a + 2][b2];
        float keepv = hi3 ? r2[a + 2][b2] : r2[a][b2];
        r3[a][b2] = keepv + __shfl_xor(sendv, 32, 64);
      }
    const size_t base = (size_t)(ut * 4 + ct) * (TPH * 1024) + (size_t)cc * 32;
#pragma unroll
    for (int a = 0; a < 2; ++a)
#pragma unroll
      for (int b2 = 0; b2 < 4; ++b2) {
        int tau = rt * 8 + bb + b2;
        if (t0 + tau < sl)
          xp[base + (size_t)tau * 1024 + (jt * 8 + ab1 + ab2 + a)] = r3[a][b2];
      }
  }
}

// ---------------- LSTM recurrent phase (cooperative, 256 WGs) ----------------
// Fence-free h exchange: write-through agent stores + L2-bypass agent loads.
// No buffer_wbl2 / buffer_inv on the per-step path.
__global__ __launch_bounds__(BLK, 1) void lstm_phase(
    int phase, const int* __restrict__ seq_lens, const float* __restrict__ Wh_f,
    const float* __restrict__ Wh_b, const float* __restrict__ b_f,
    const float* __restrict__ b_b, const float* __restrict__ W_out,
    const float* __restrict__ xp, float* __restrict__ hbuf, float* __restrict__ cbuf,
    unsigned long long* __restrict__ featsFix, unsigned* __restrict__ bar) {
  extern __shared__ float sm[];
  float* wS = sm + LW_OFF;
  float* hS = sm + LH_OFF;
  float* gS = sm + LG_OFF;
  float* xpS = sm + LXP_OFF;
  float* hlS = sm + LHL_OFF;
  float* cstS = sm + LCS_OFF;
  float* biasS = sm + LBI_OFF;
  float* woutS = sm + LWO_OFF;
  int* slS = (int*)(sm + LSL_OFF);
  int* mslS = (int*)(sm + LMX_OFF);

  const int tid = threadIdx.x;
  const int bid = blockIdx.x;
  const int ut = bid & 63, ct = bid >> 6;
  const int u0 = ut * 8, ch0 = ct * 32, dir = ct >> 1;
  const float* Wh = dir ? Wh_b : Wh_f;
  const float* bb = dir ? b_b : b_f;

  if (tid < 32) slS[tid] = seq_lens[((ct & 1) << 5) + tid];
  __syncthreads();
  if (tid == 0) {
    int m = 0;
    for (int c = 0; c < 32; ++c) m = max(m, slS[c]);
    *mslS = m;
  }
  __syncthreads();
  const int gmax = *mslS;
  const int t0 = phase * TPH;
  if (t0 >= gmax) return;  // group-uniform exit

  for (int j = 0; j < 32; ++j) {
    int row = (j >> 3) * 512 + u0 + (j & 7);
    for (int ee = tid; ee < 512; ee += BLK)
      wS[ee * 32 + ((((j >> 2) ^ (ee & 7)) << 2) | (j & 3))] = Wh[row * 512 + ee];
  }
  if (tid < 96) woutS[tid] = W_out[(tid >> 3) * 1024 + dir * 512 + u0 + (tid & 7)];
  if (tid < 32) biasS[tid] = bb[(tid >> 3) * 512 + u0 + (tid & 7)];
  cstS[tid] = cbuf[bid * 256 + tid];
  __syncthreads();

  const int lane = tid & 63, w = tid >> 6;
  const int tp = lane & 15, jt = tp & 3, ct2 = tp >> 2;
  const int es = w * 4 + (lane >> 4);
  const int esw = es & 7;
  const int nst = min(TPH, gmax - t0);

  const float* wpA = wS + es * 32 + (((jt * 2) ^ esw) << 2);
  const float* wpB = wS + es * 32 + (((jt * 2 + 1) ^ esw) << 2);
  const float* hpA = hS + es * 32 + (((ct2 * 2) ^ esw) << 2);
  const float* hpB = hS + es * 32 + (((ct2 * 2 + 1) ^ esw) << 2);

  float4 xr = *(const float4*)(xp + ((size_t)(ut * 4 + ct) * TPH + 0) * 1024 + tid * 4);

  for (int tl = 0; tl < nst; ++tl) {
    const int t = t0 + tl;
    const float* hcur = hbuf + (t & 1) * 65536;
    float* hnxt = hbuf + ((t + 1) & 1) * 65536;

    // ---- wait: h(t) published (flag >= t); no acquire fence needed (bypass loads) ----
    if (tid == 0) {
      while (__hip_atomic_load(&bar[ct * 64], __ATOMIC_RELAXED,
                               __HIP_MEMORY_SCOPE_AGENT) < (unsigned)t) {}
    }
    __syncthreads();

    // [A] stage h slice -> regs (L2-bypass, pipelined) -> LDS (swizzled)
    {
      u64t hq[32];
#pragma unroll
      for (int it = 0; it < 16; ++it) {
        int u = it * 32 + (tid >> 3), q = tid & 7;
        const u64t* p = (const u64t*)(hcur + u * 128 + ch0 + q * 4);
        hq[2 * it] = __hip_atomic_load(p, __ATOMIC_RELAXED, __HIP_MEMORY_SCOPE_AGENT);
        hq[2 * it + 1] =
            __hip_atomic_load(p + 1, __ATOMIC_RELAXED, __HIP_MEMORY_SCOPE_AGENT);
      }
#pragma unroll
      for (int it = 0; it < 16; ++it) {
        int u = it * 32 + (tid >> 3), q = tid & 7;
        union { u64t q2[2]; float4 v; } uu2;
        uu2.q2[0] = hq[2 * it];
        uu2.q2[1] = hq[2 * it + 1];
        *(float4*)(hS + u * 32 + ((q ^ (u & 7)) << 2)) = uu2.v;
      }
    }
    {
      int c = tid >> 3, j4 = tid & 7;
      float* d = xpS + c * 33 + j4 * 4;
      d[0] = xr.x; d[1] = xr.y; d[2] = xr.z; d[3] = xr.w;
    }
    if (tl + 1 < nst)
      xr = *(const float4*)(xp + ((size_t)(ut * 4 + ct) * TPH + (tl + 1)) * 1024 + tid * 4);
    __syncthreads();

    // [B] 32x32x512 matmul: 8x8 register tile
    float acc[8][8];
#pragma unroll
    for (int a = 0; a < 8; ++a)
#pragma unroll
      for (int b2 = 0; b2 < 8; ++b2) acc[a][b2] = 0.f;
    for (int io = 0; io < 4; ++io) {
#pragma unroll
      for (int ii = 0; ii < 8; ++ii) {
        const int off = (io * 8 + ii) * 512;
        const float4 w0 = *(const float4*)(wpA + off);
        const float4 w1 = *(const float4*)(wpB + off);
        const float4 x0 = *(const float4*)(hpA + off);
        const float4 x1 = *(const float4*)(hpB + off);
        float wv[8] = {w0.x, w0.y, w0.z, w0.w, w1.x, w1.y, w1.z, w1.w};
        float xv[8] = {x0.x, x0.y, x0.z, x0.w, x1.x, x1.y, x1.z, x1.w};
#pragma unroll
        for (int a = 0; a < 8; ++a)
#pragma unroll
          for (int b2 = 0; b2 < 8; ++b2) acc[a][b2] = fmaf(wv[a], xv[b2], acc[a][b2]);
      }
    }

    // in-wave butterfly reduce-scatter over es lane-bits 16,32
    const bool hi1 = (lane & 16) != 0;
    float r1[4][8];
#pragma unroll
    for (int a = 0; a < 4; ++a)
#pragma unroll
      for (int b2 = 0; b2 < 8; ++b2) {
        float sendv = hi1 ? acc[a][b2] : acc[a + 4][b2];
        float keepv = hi1 ? acc[a + 4][b2] : acc[a][b2];
        r1[a][b2] = keepv + __shfl_xor(sendv, 16, 64);
      }
    const bool hi2 = (lane & 32) != 0;
    float r2[4][4];
#pragma unroll
    for (int a = 0; a < 4; ++a)
#pragma unroll
      for (int b2 = 0; b2 < 4; ++b2) {
        float sendv = hi2 ? r1[a][b2] : r1[a][b2 + 4];
        float keepv = hi2 ? r1[a][b2 + 4] : r1[a][b2];
        r2[a][b2] = keepv + __shfl_xor(sendv, 32, 64);
      }
    const int ab = hi1 ? 4 : 0, bbs = hi2 ? 4 : 0;
#pragma unroll
    for (int a = 0; a < 4; ++a) {
      float4 v = make_float4(r2[a][0], r2[a][1], r2[a][2], r2[a][3]);
      *(float4*)(gS + w * 1024 + (jt * 8 + ab + a) * 32 + ct2 * 8 + bbs) = v;
    }
    __syncthreads();

    // [C] epilogue: combine 4 wave-partials + xp + bias -> gates -> c,h
    {
      const int uu = tid >> 5, c = tid & 31;
      const int slc = slS[c];
      float s0 = 0.f, s1 = 0.f, s2 = 0.f, s3 = 0.f;
#pragma unroll
      for (int w2 = 0; w2 < 4; ++w2) {
        const float* gp = gS + w2 * 1024 + uu * 32 + c;
        s0 += gp[0];
        s1 += gp[256];
        s2 += gp[512];
        s3 += gp[768];
      }
      const bool xvalid = (t < slc);
      float x0 = xvalid ? xpS[c * 33 + uu] : 0.f;
      float x1 = xvalid ? xpS[c * 33 + 8 + uu] : 0.f;
      float x2 = xvalid ? xpS[c * 33 + 16 + uu] : 0.f;
      float x3 = xvalid ? xpS[c * 33 + 24 + uu] : 0.f;
      float iv = s0 + x0 + biasS[uu];
      float fv = s1 + x1 + biasS[8 + uu];
      float gv = s2 + x2 + biasS[16 + uu];
      float ov = s3 + x3 + biasS[24 + uu];
      float cn = sigm(fv) * cstS[uu * 32 + c] + sigm(iv) * tanhf(gv);
      float hn = sigm(ov) * tanhf(cn);
      cstS[uu * 32 + c] = cn;
      // write-through agent store: publishes h without wbl2
      __hip_atomic_store(&hnxt[(u0 + uu) * 128 + ch0 + c], hn, __ATOMIC_RELAXED,
                         __HIP_MEMORY_SCOPE_AGENT);
      hlS[uu * 32 + c] = hn;
    }
    // drain this wave's h stores to the coherence point, then block-wide sync
    asm volatile("s_waitcnt vmcnt(0)" ::: "memory");
    __syncthreads();

    // ---- arrive: counter RMW + broadcast flag (relaxed agent; no release fence) ----
    if (tid == 0) {
      unsigned o = __hip_atomic_fetch_add(&bar[ct * 64 + 16], 1u, __ATOMIC_RELAXED,
                                          __HIP_MEMORY_SCOPE_AGENT);
      if (o == (unsigned)(t + 1) * 64u - 1u)
        __hip_atomic_store(&bar[ct * 64], (unsigned)(t + 1), __ATOMIC_RELAXED,
                           __HIP_MEMORY_SCOPE_AGENT);
    }

    // feats partial (fixed-point atomics) — issued after arrive, drains during next poll
    for (int base = 0; base < 384; base += 256) {
      int idx = base + tid;
      if (idx < 384) {
        int c = idx / 12, k = idx % 12;
        int sl = slS[c];
        if (t < sl) {
          float pacc = 0.f;
#pragma unroll
          for (int uu = 0; uu < 8; ++uu) pacc += hlS[uu * 32 + c] * woutS[k * 8 + uu];
          int tt = dir ? (sl - 1 - t) : t;
          double y = (double)pacc * FIX_SCALE;
          long long q = (long long)(y + (y >= 0.0 ? 0.5 : -0.5));
          atomicAdd(&featsFix[((size_t)(((ct & 1) << 5) + c) * 512 + tt) * 12 + k],
                    (unsigned long long)q);
        }
      }
    }
  }
  cbuf[bid * 256 + tid] = cstS[tid];
}

// ---------------- viterbi: 64 blocks (one b each), fv replicated via shfl ----------------
__global__ __launch_bounds__(64) void viterbi2(
    const int* __restrict__ seq_lens, const float* __restrict__ b_out,
    const float* __restrict__ transitions,
    const unsigned long long* __restrict__ featsFix,
    unsigned char* __restrict__ bps, float* __restrict__ out) {
  __shared__ unsigned char tagB[512];
  const int b = blockIdx.x;
  const int lane = threadIdx.x;
  const int k = lane < 12 ? lane : 0;
  const int sl = seq_lens[b];
  float trow[12];
#pragma unroll
  for (int p = 0; p < 12; ++p) trow[p] = transitions[k * 12 + p];
  const float bo = b_out[k];
  float fvv[12];
#pragma unroll
  for (int p = 0; p < 12; ++p) fvv[p] = (p == START_TAG) ? 0.f : -10000.f;
  const unsigned long long* fbase = featsFix + (size_t)b * 512 * 12;
  long long fx = (long long)fbase[k];
  for (int t = 0; t < TSEQ; ++t) {
    float best = fvv[0] + trow[0];
    int arg = 0;
#pragma unroll
    for (int p = 1; p < 12; ++p) {
      float v = fvv[p] + trow[p];
      if (v > best) { best = v; arg = p; }
    }
    float feat = (float)((double)fx * FIX_INV) + bo;
    if (t + 1 < TSEQ) fx = (long long)fbase[(t + 1) * 12 + k];
    const bool m = t < sl;
    float nv = m ? (best + feat) : fvv[k];
    int bpv = m ? arg : k;
    if (lane < 12) bps[((size_t)t * 64 + b) * 12 + lane] = (unsigned char)bpv;
#pragma unroll
    for (int p = 0; p < 12; ++p) fvv[p] = __shfl(nv, p, 64);
  }
  __syncthreads();
  if (lane == 0) {
    float best = fvv[0] + transitions[STOP_TAG * 12 + 0];
    int arg = 0;
    for (int kk = 1; kk < 12; ++kk) {
      float v = fvv[kk] + transitions[STOP_TAG * 12 + kk];
      if (v > best) { best = v; arg = kk; }
    }
    out[b] = best;
    int tag = arg;
    const uint32_t* rowp = (const uint32_t*)bps;
    uint32_t r0, r1, r2;
    {
      size_t off = ((size_t)511 * 64 + b) * 3;
      r0 = rowp[off]; r1 = rowp[off + 1]; r2 = rowp[off + 2];
    }
    for (int t = 511; t >= 0; --t) {
      uint32_t n0 = 0, n1 = 0, n2 = 0;
      if (t > 0) {
        size_t off = ((size_t)(t - 1) * 64 + b) * 3;
        n0 = rowp[off]; n1 = rowp[off + 1]; n2 = rowp[off + 2];
      }
      tagB[t] = (unsigned char)tag;
      uint32_t sel = (tag < 4) ? (r0 >> (tag * 8))
                   : (tag < 8) ? (r1 >> ((tag - 4) * 8))
                               : (r2 >> ((tag - 8) * 8));
      tag = (int)(sel & 0xffu);
      r0 = n0; r1 = n1; r2 = n2;
    }
  }
  __syncthreads();
  for (int t = lane; t < 512; t += 64) out[64 + (size_t)b * 512 + t] = (float)tagB[t];
}

extern "C" void kernel_launch(void* const* d_in, const int* in_sizes, int n_in,
                              void* d_out, int out_size, void* d_ws, size_t ws_size,
                              hipStream_t stream) {
  (void)in_sizes; (void)n_in; (void)out_size; (void)ws_size;
  const int* sentence = (const int*)d_in[0];
  const int* seq_lens = (const int*)d_in[1];
  const float* embed = (const float*)d_in[2];
  const float* Wi_f = (const float*)d_in[3];
  const float* Wh_f = (const float*)d_in[4];
  const float* b_f = (const float*)d_in[5];
  const float* Wi_b = (const float*)d_in[6];
  const float* Wh_b = (const float*)d_in[7];
  const float* b_b = (const float*)d_in[8];
  const float* h0 = (const float*)d_in[9];
  const float* c0 = (const float*)d_in[10];
  const float* W_out = (const float*)d_in[11];
  const float* b_out = (const float*)d_in[12];
  const float* trans = (const float*)d_in[13];

  char* ws = (char*)d_ws;
  unsigned* bar = (unsigned*)ws;
  unsigned long long* featsFix = (unsigned long long*)(ws + FEATS_OFF);
  float* hbuf = (float*)(ws + HBUF_OFF);
  float* cbuf = (float*)(ws + CBUF_OFF);
  unsigned char* bps = (unsigned char*)(ws + BPS_OFF);
  float* xpw = (float*)(ws + XP_OFF);

  hipMemsetAsync(d_ws, 0, FEATS_OFF + FEATS_BYTES, stream);  // bar + featsFix

  hipFuncSetAttribute((const void*)lstm_phase,
                      hipFuncAttributeMaxDynamicSharedMemorySize, LSTM_SMEM_BYTES);
  hipFuncSetAttribute((const void*)pre_gemm,
                      hipFuncAttributeMaxDynamicSharedMemorySize, PRE_SMEM_BYTES);

  init_state<<<dim3(512), dim3(256), 0, stream>>>(h0, c0, hbuf, cbuf);

  for (int p = 0; p < NPH; ++p) {
    pre_gemm<<<dim3(128, 8), dim3(BLK), PRE_SMEM_BYTES, stream>>>(
        p, sentence, seq_lens, embed, Wi_f, Wi_b, xpw);
    int pv = p;
    void* kargs[] = {(void*)&pv,    (void*)&seq_lens, (void*)&Wh_f,     (void*)&Wh_b,
                     (void*)&b_f,   (void*)&b_b,      (void*)&W_out,    (void*)&xpw,
                     (void*)&hbuf,  (void*)&cbuf,     (void*)&featsFix, (void*)&bar};
    hipLaunchCooperativeKernel((const void*)lstm_phase, dim3(NWG), dim3(BLK), kargs,
                               LSTM_SMEM_BYTES, stream);
  }
  viterbi2<<<dim3(64), dim3(64), 0, stream>>>(seq_lens, b_out, trans, featsFix, bps,
                                              (float*)d_out);
}